// Round 1
// baseline (3286.104 us; speedup 1.0000x reference)
//
#include <hip/hip_runtime.h>
#include <math.h>

#define N_NODES 100000
#define N_EDGES 800000
#define HID 128
#define HEADS 4
#define HD 32

// order-preserving float<->uint for atomicMax on signed floats
__device__ __forceinline__ unsigned int enc_f32(float f) {
    unsigned int b = __float_as_uint(f);
    return (b & 0x80000000u) ? ~b : (b | 0x80000000u);
}
__device__ __forceinline__ float dec_f32(unsigned int u) {
    unsigned int b = (u & 0x80000000u) ? (u & 0x7FFFFFFFu) : ~u;
    return __uint_as_float(b);
}

// ---------------------------------------------------------------------------
// Kernel A: fused projections  Q=xWq+bq, K=xWk+bk, V=xWv+bv, S=xWs+bs
// 64 rows x 64 cols per block; 8 col-tiles (4 matrices x 2 halves).
// ---------------------------------------------------------------------------
__global__ __launch_bounds__(256) void proj_gemm(
    const float* __restrict__ x,
    const float* __restrict__ Wq, const float* __restrict__ bq,
    const float* __restrict__ Wk, const float* __restrict__ bk,
    const float* __restrict__ Wv, const float* __restrict__ bv,
    const float* __restrict__ Ws, const float* __restrict__ bs,
    float* __restrict__ Q, float* __restrict__ K,
    float* __restrict__ V, float* __restrict__ S)
{
    __shared__ float xs[64][133];    // +5 pad: a-reads land 2-way (free)
    __shared__ float wsh[128][68];   // 16B-aligned rows for float4 r/w

    const int bid = blockIdx.x;
    const int ct  = bid & 7;
    const int rt  = bid >> 3;
    const int rb  = rt * 64;
    const int m   = ct >> 1;
    const int cb  = (ct & 1) * 64;

    const float* W    = (m == 0) ? Wq : (m == 1) ? Wk : (m == 2) ? Wv : Ws;
    const float* bias = (m == 0) ? bq : (m == 1) ? bk : (m == 2) ? bv : bs;
    float*       outp = (m == 0) ? Q  : (m == 1) ? K  : (m == 2) ? V  : S;

    const int tid = threadIdx.x;

    // stage x tile (64 rows x 128 k), coalesced float4 loads
    #pragma unroll
    for (int it = 0; it < 8; ++it) {
        int idx = it * 256 + tid;
        int r = idx >> 5, kq = idx & 31;
        int row = rb + r;
        float4 v4 = make_float4(0.f, 0.f, 0.f, 0.f);
        if (row < N_NODES) v4 = *(const float4*)(x + row * HID + kq * 4);
        xs[r][kq * 4 + 0] = v4.x;
        xs[r][kq * 4 + 1] = v4.y;
        xs[r][kq * 4 + 2] = v4.z;
        xs[r][kq * 4 + 3] = v4.w;
    }
    // stage W tile (128 k x 64 cols)
    #pragma unroll
    for (int it = 0; it < 8; ++it) {
        int idx = it * 256 + tid;
        int kw = idx >> 4, cq = idx & 15;
        float4 v4 = *(const float4*)(W + kw * HID + cb + cq * 4);
        *(float4*)&wsh[kw][cq * 4] = v4;
    }
    __syncthreads();

    const int c0 = (tid & 15) * 4;
    const int r0 = (tid >> 4) * 4;
    float acc[4][4];
    #pragma unroll
    for (int i = 0; i < 4; ++i)
        #pragma unroll
        for (int j = 0; j < 4; ++j) acc[i][j] = 0.f;

    #pragma unroll 4
    for (int k = 0; k < 128; ++k) {
        float4 b4 = *(const float4*)&wsh[k][c0];
        #pragma unroll
        for (int i = 0; i < 4; ++i) {
            float a = xs[r0 + i][k];
            acc[i][0] += a * b4.x;
            acc[i][1] += a * b4.y;
            acc[i][2] += a * b4.z;
            acc[i][3] += a * b4.w;
        }
    }

    float4 bi = *(const float4*)(bias + cb + c0);
    #pragma unroll
    for (int i = 0; i < 4; ++i) {
        int row = rb + r0 + i;
        if (row < N_NODES) {
            float4 o;
            o.x = acc[i][0] + bi.x;
            o.y = acc[i][1] + bi.y;
            o.z = acc[i][2] + bi.z;
            o.w = acc[i][3] + bi.w;
            *(float4*)(outp + row * HID + cb + c0) = o;
        }
    }
}

// ---------------------------------------------------------------------------
// Kernel B: per-edge attention logits + fused segment max (atomicMax, encoded)
// 16 lanes per edge; lane l16 handles 8 contiguous floats (head = l16/4).
// ---------------------------------------------------------------------------
__global__ __launch_bounds__(256) void edge_logits(
    const int* __restrict__ ei,
    const float* __restrict__ Q, const float* __restrict__ K,
    float* __restrict__ alpha, unsigned int* __restrict__ amaxU)
{
    const int tid  = threadIdx.x;
    const int lane = tid & 63;
    const int wid  = tid >> 6;
    const int l16  = lane & 15;
    const int eloc = lane >> 4;
    const int e    = blockIdx.x * 16 + wid * 4 + eloc;
    if (e >= N_EDGES) return;

    const int src = ei[e];
    const int dst = ei[N_EDGES + e];

    const float4* qp = (const float4*)(Q + dst * HID + l16 * 8);
    const float4* kp = (const float4*)(K + src * HID + l16 * 8);
    float4 q0 = qp[0], q1 = qp[1];
    float4 k0 = kp[0], k1 = kp[1];
    float p = q0.x * k0.x + q0.y * k0.y + q0.z * k0.z + q0.w * k0.w
            + q1.x * k1.x + q1.y * k1.y + q1.z * k1.z + q1.w * k1.w;
    p += __shfl_xor(p, 1);
    p += __shfl_xor(p, 2);
    float a = p * 0.1767766952966369f;  // 1/sqrt(32)

    const int h = l16 >> 2;
    if ((l16 & 3) == 0) {
        alpha[e * 4 + h] = a;
        atomicMax(&amaxU[dst * 4 + h], enc_f32(a));
    }
}

// ---------------------------------------------------------------------------
// Kernel C: exp, denom accumulation, unnormalized weighted scatter of V
// (division by denom deferred to finalize — it is linear).
// ---------------------------------------------------------------------------
__global__ __launch_bounds__(256) void edge_scatter(
    const int* __restrict__ ei,
    const float* __restrict__ alpha, const unsigned int* __restrict__ amaxU,
    const float* __restrict__ V,
    float* __restrict__ denom, float* __restrict__ outacc)
{
    const int tid  = threadIdx.x;
    const int lane = tid & 63;
    const int wid  = tid >> 6;
    const int l16  = lane & 15;
    const int eloc = lane >> 4;
    const int e    = blockIdx.x * 16 + wid * 4 + eloc;
    if (e >= N_EDGES) return;

    const int src = ei[e];
    const int dst = ei[N_EDGES + e];
    const int h   = l16 >> 2;

    float am = dec_f32(amaxU[dst * 4 + h]);
    float ex = expf(alpha[e * 4 + h] - am);
    if ((l16 & 3) == 0) atomicAdd(&denom[dst * 4 + h], ex);

    const float4* vp = (const float4*)(V + src * HID + l16 * 8);
    float4 v0 = vp[0], v1 = vp[1];
    float* op = outacc + dst * HID + l16 * 8;
    atomicAdd(op + 0, ex * v0.x);
    atomicAdd(op + 1, ex * v0.y);
    atomicAdd(op + 2, ex * v0.z);
    atomicAdd(op + 3, ex * v0.w);
    atomicAdd(op + 4, ex * v1.x);
    atomicAdd(op + 5, ex * v1.y);
    atomicAdd(op + 6, ex * v1.z);
    atomicAdd(op + 7, ex * v1.w);
}

// ---------------------------------------------------------------------------
// Kernel D: out = acc/(denom+eps) + S; LayerNorm over 128; one wave per node.
// ---------------------------------------------------------------------------
__global__ __launch_bounds__(256) void finalize(
    const float* __restrict__ S, const float* __restrict__ denom,
    const float* __restrict__ gamma, const float* __restrict__ beta,
    float* __restrict__ out)
{
    const int tid  = threadIdx.x;
    const int lane = tid & 63;
    const int wid  = tid >> 6;
    const int node = blockIdx.x * 4 + wid;
    if (node >= N_NODES) return;

    const int j = lane * 2;
    const int h = j >> 5;

    float2 a = *(const float2*)(out + node * HID + j);
    float2 s = *(const float2*)(S + node * HID + j);
    float inv = 1.0f / (denom[node * 4 + h] + 1e-16f);
    float v0 = a.x * inv + s.x;
    float v1 = a.y * inv + s.y;

    float sum = v0 + v1;
    float sq  = v0 * v0 + v1 * v1;
    #pragma unroll
    for (int off = 1; off < 64; off <<= 1) {
        sum += __shfl_xor(sum, off);
        sq  += __shfl_xor(sq, off);
    }
    float mean = sum * (1.0f / 128.0f);
    float var  = sq * (1.0f / 128.0f) - mean * mean;
    float rstd = rsqrtf(var + 1e-5f);

    float2 g  = *(const float2*)(gamma + j);
    float2 bb = *(const float2*)(beta + j);
    float2 o;
    o.x = (v0 - mean) * rstd * g.x + bb.x;
    o.y = (v1 - mean) * rstd * g.y + bb.y;
    *(float2*)(out + node * HID + j) = o;
}

// ---------------------------------------------------------------------------
extern "C" void kernel_launch(void* const* d_in, const int* in_sizes, int n_in,
                              void* d_out, int out_size, void* d_ws, size_t ws_size,
                              hipStream_t stream) {
    const float* x  = (const float*)d_in[0];
    const int*   ei = (const int*)d_in[1];
    const float* Wq = (const float*)d_in[2];
    const float* bq = (const float*)d_in[3];
    const float* Wk = (const float*)d_in[4];
    const float* bk = (const float*)d_in[5];
    const float* Wv = (const float*)d_in[6];
    const float* bv = (const float*)d_in[7];
    const float* Ws = (const float*)d_in[8];
    const float* bs = (const float*)d_in[9];
    const float* gamma = (const float*)d_in[10];
    const float* beta  = (const float*)d_in[11];
    float* out = (float*)d_out;

    // workspace layout (floats)
    float* Q = (float*)d_ws;
    float* K = Q + (size_t)N_NODES * HID;
    float* V = K + (size_t)N_NODES * HID;
    float* S = V + (size_t)N_NODES * HID;
    float* alpha = S + (size_t)N_NODES * HID;
    unsigned int* amaxU = (unsigned int*)(alpha + (size_t)N_EDGES * HEADS);
    float* denom = (float*)(amaxU + (size_t)N_NODES * HEADS);

    hipMemsetAsync(d_out, 0, (size_t)N_NODES * HID * sizeof(float), stream);
    hipMemsetAsync(amaxU, 0, (size_t)N_NODES * HEADS * sizeof(unsigned int), stream);
    hipMemsetAsync(denom, 0, (size_t)N_NODES * HEADS * sizeof(float), stream);

    const int row_tiles = (N_NODES + 63) / 64;          // 1563
    proj_gemm<<<row_tiles * 8, 256, 0, stream>>>(x, Wq, bq, Wk, bk, Wv, bv,
                                                 Ws, bs, Q, K, V, S);
    const int eblocks = (N_EDGES + 15) / 16;            // 50000
    edge_logits<<<eblocks, 256, 0, stream>>>(ei, Q, K, alpha, amaxU);
    edge_scatter<<<eblocks, 256, 0, stream>>>(ei, alpha, amaxU, V, denom, out);
    finalize<<<(N_NODES + 3) / 4, 256, 0, stream>>>(S, denom, gamma, beta, out);
}

// Round 2
// 658.114 us; speedup vs baseline: 4.9932x; 4.9932x over previous
//
#include <hip/hip_runtime.h>
#include <math.h>

#define N_NODES 100000
#define N_EDGES 800000
#define HID 128
#define HEADS 4
#define HD 32

// ---------------------------------------------------------------------------
// Kernel A: fused projections  Q=xWq+bq, K=xWk+bk, V=xWv+bv, S=xWs+bs
// 64 rows x 64 cols per block; 8 col-tiles (4 matrices x 2 halves).
// ---------------------------------------------------------------------------
__global__ __launch_bounds__(256) void proj_gemm(
    const float* __restrict__ x,
    const float* __restrict__ Wq, const float* __restrict__ bq,
    const float* __restrict__ Wk, const float* __restrict__ bk,
    const float* __restrict__ Wv, const float* __restrict__ bv,
    const float* __restrict__ Ws, const float* __restrict__ bs,
    float* __restrict__ Q, float* __restrict__ K,
    float* __restrict__ V, float* __restrict__ S)
{
    __shared__ float xs[64][133];    // +5 pad: a-reads land 2-way (free)
    __shared__ float wsh[128][68];   // 16B-aligned rows for float4 r/w

    const int bid = blockIdx.x;
    const int ct  = bid & 7;
    const int rt  = bid >> 3;
    const int rb  = rt * 64;
    const int m   = ct >> 1;
    const int cb  = (ct & 1) * 64;

    const float* W    = (m == 0) ? Wq : (m == 1) ? Wk : (m == 2) ? Wv : Ws;
    const float* bias = (m == 0) ? bq : (m == 1) ? bk : (m == 2) ? bv : bs;
    float*       outp = (m == 0) ? Q  : (m == 1) ? K  : (m == 2) ? V  : S;

    const int tid = threadIdx.x;

    #pragma unroll
    for (int it = 0; it < 8; ++it) {
        int idx = it * 256 + tid;
        int r = idx >> 5, kq = idx & 31;
        int row = rb + r;
        float4 v4 = make_float4(0.f, 0.f, 0.f, 0.f);
        if (row < N_NODES) v4 = *(const float4*)(x + row * HID + kq * 4);
        xs[r][kq * 4 + 0] = v4.x;
        xs[r][kq * 4 + 1] = v4.y;
        xs[r][kq * 4 + 2] = v4.z;
        xs[r][kq * 4 + 3] = v4.w;
    }
    #pragma unroll
    for (int it = 0; it < 8; ++it) {
        int idx = it * 256 + tid;
        int kw = idx >> 4, cq = idx & 15;
        float4 v4 = *(const float4*)(W + kw * HID + cb + cq * 4);
        *(float4*)&wsh[kw][cq * 4] = v4;
    }
    __syncthreads();

    const int c0 = (tid & 15) * 4;
    const int r0 = (tid >> 4) * 4;
    float acc[4][4];
    #pragma unroll
    for (int i = 0; i < 4; ++i)
        #pragma unroll
        for (int j = 0; j < 4; ++j) acc[i][j] = 0.f;

    #pragma unroll 4
    for (int k = 0; k < 128; ++k) {
        float4 b4 = *(const float4*)&wsh[k][c0];
        #pragma unroll
        for (int i = 0; i < 4; ++i) {
            float a = xs[r0 + i][k];
            acc[i][0] += a * b4.x;
            acc[i][1] += a * b4.y;
            acc[i][2] += a * b4.z;
            acc[i][3] += a * b4.w;
        }
    }

    float4 bi = *(const float4*)(bias + cb + c0);
    #pragma unroll
    for (int i = 0; i < 4; ++i) {
        int row = rb + r0 + i;
        if (row < N_NODES) {
            float4 o;
            o.x = acc[i][0] + bi.x;
            o.y = acc[i][1] + bi.y;
            o.z = acc[i][2] + bi.z;
            o.w = acc[i][3] + bi.w;
            *(float4*)(outp + row * HID + cb + c0) = o;
        }
    }
}

// ---------------------------------------------------------------------------
// CSR build: histogram of dst, exclusive scan, slot fill.
// ---------------------------------------------------------------------------
__global__ __launch_bounds__(256) void histo(const int* __restrict__ ei,
                                             int* __restrict__ deg)
{
    int e = blockIdx.x * 256 + threadIdx.x;
    if (e < N_EDGES) atomicAdd(&deg[ei[N_EDGES + e]], 1);
}

// single-block hierarchical exclusive scan (wave shfl scan + LDS wave sums)
__global__ __launch_bounds__(1024) void scan_deg(const int* __restrict__ deg,
                                                 int* __restrict__ rowptr)
{
    __shared__ int wsum[16];
    __shared__ int carry_sh;
    const int tid = threadIdx.x, lane = tid & 63, wid = tid >> 6;
    if (tid == 0) carry_sh = 0;
    __syncthreads();
    for (int base = 0; base < N_NODES; base += 1024) {
        int v = (base + tid < N_NODES) ? deg[base + tid] : 0;
        int x = v;
        #pragma unroll
        for (int off = 1; off < 64; off <<= 1) {
            int t = __shfl_up(x, off);
            if (lane >= off) x += t;
        }
        if (lane == 63) wsum[wid] = x;
        __syncthreads();                       // wsum visible; carry_sh stable
        int wpre = 0;
        #pragma unroll
        for (int w = 0; w < 15; ++w) { if (w < wid) wpre += wsum[w]; }
        if (base + tid < N_NODES) rowptr[base + tid] = carry_sh + wpre + x - v;
        __syncthreads();                       // all reads of carry_sh done
        if (tid == 1023) carry_sh += wpre + x;
        __syncthreads();                       // update visible before next iter
    }
    if (tid == 0) rowptr[N_NODES] = carry_sh;
}

__global__ __launch_bounds__(256) void csr_fill(const int* __restrict__ ei,
                                                const int* __restrict__ rowptr,
                                                int* __restrict__ fillctr,
                                                int* __restrict__ csr_src,
                                                int* __restrict__ csr_dst)
{
    int e = blockIdx.x * 256 + threadIdx.x;
    if (e >= N_EDGES) return;
    int src = ei[e], dst = ei[N_EDGES + e];
    int pos = rowptr[dst] + atomicAdd(&fillctr[dst], 1);
    csr_src[pos] = src;
    csr_dst[pos] = dst;
}

// ---------------------------------------------------------------------------
// Kernel B: per-slot attention logits (CSR order -> contiguous alpha writes).
// 16 lanes per slot.
// ---------------------------------------------------------------------------
__global__ __launch_bounds__(256) void edge_logits(
    const int* __restrict__ csr_src, const int* __restrict__ csr_dst,
    const float* __restrict__ Q, const float* __restrict__ K,
    float* __restrict__ alpha)
{
    const int tid  = threadIdx.x;
    const int lane = tid & 63;
    const int wid  = tid >> 6;
    const int l16  = lane & 15;
    const int eloc = lane >> 4;
    const int e    = blockIdx.x * 16 + wid * 4 + eloc;
    if (e >= N_EDGES) return;

    const int src = csr_src[e];
    const int dst = csr_dst[e];

    const float4* qp = (const float4*)(Q + dst * HID + l16 * 8);
    const float4* kp = (const float4*)(K + src * HID + l16 * 8);
    float4 q0 = qp[0], q1 = qp[1];
    float4 k0 = kp[0], k1 = kp[1];
    float p = q0.x * k0.x + q0.y * k0.y + q0.z * k0.z + q0.w * k0.w
            + q1.x * k1.x + q1.y * k1.y + q1.z * k1.z + q1.w * k1.w;
    p += __shfl_xor(p, 1);
    p += __shfl_xor(p, 2);
    float a = p * 0.1767766952966369f;  // 1/sqrt(32)

    const int h = l16 >> 2;
    if ((l16 & 3) == 0) alpha[e * 4 + h] = a;
}

// ---------------------------------------------------------------------------
// Kernel C: per-node softmax + V gather + skip + LayerNorm (no atomics).
// One wave per node; lane covers 2 output dims (float2).
// ---------------------------------------------------------------------------
__global__ __launch_bounds__(256) void node_gather(
    const int* __restrict__ rowptr, const int* __restrict__ csr_src,
    const float* __restrict__ alpha, const float* __restrict__ V,
    const float* __restrict__ S,
    const float* __restrict__ gamma, const float* __restrict__ beta,
    float* __restrict__ out)
{
    const int tid  = threadIdx.x;
    const int lane = tid & 63;
    const int wid  = tid >> 6;
    const int node = blockIdx.x * 4 + wid;
    if (node >= N_NODES) return;

    const int j = lane * 2;
    const int h = j >> 5;
    const int r0 = rowptr[node], r1 = rowptr[node + 1];

    float m = -INFINITY;
    for (int p = r0; p < r1; ++p) m = fmaxf(m, alpha[p * 4 + h]);

    float den = 0.f, accx = 0.f, accy = 0.f;
    for (int p = r0; p < r1; ++p) {
        float ex = __expf(alpha[p * 4 + h] - m);
        den += ex;
        int src = csr_src[p];
        float2 v = *(const float2*)(V + src * HID + j);
        accx += ex * v.x;
        accy += ex * v.y;
    }

    float inv = 1.0f / (den + 1e-16f);
    float2 s = *(const float2*)(S + node * HID + j);
    float v0 = accx * inv + s.x;
    float v1 = accy * inv + s.y;

    float sum = v0 + v1;
    float sq  = v0 * v0 + v1 * v1;
    #pragma unroll
    for (int off = 1; off < 64; off <<= 1) {
        sum += __shfl_xor(sum, off);
        sq  += __shfl_xor(sq, off);
    }
    float mean = sum * (1.0f / 128.0f);
    float var  = sq * (1.0f / 128.0f) - mean * mean;
    float rstd = rsqrtf(var + 1e-5f);

    float2 g  = *(const float2*)(gamma + j);
    float2 bb = *(const float2*)(beta + j);
    float2 o;
    o.x = (v0 - mean) * rstd * g.x + bb.x;
    o.y = (v1 - mean) * rstd * g.y + bb.y;
    *(float2*)(out + node * HID + j) = o;
}

// ---------------------------------------------------------------------------
extern "C" void kernel_launch(void* const* d_in, const int* in_sizes, int n_in,
                              void* d_out, int out_size, void* d_ws, size_t ws_size,
                              hipStream_t stream) {
    const float* x  = (const float*)d_in[0];
    const int*   ei = (const int*)d_in[1];
    const float* Wq = (const float*)d_in[2];
    const float* bq = (const float*)d_in[3];
    const float* Wk = (const float*)d_in[4];
    const float* bk = (const float*)d_in[5];
    const float* Wv = (const float*)d_in[6];
    const float* bv = (const float*)d_in[7];
    const float* Ws = (const float*)d_in[8];
    const float* bs = (const float*)d_in[9];
    const float* gamma = (const float*)d_in[10];
    const float* beta  = (const float*)d_in[11];
    float* out = (float*)d_out;

    // workspace layout (floats / ints)
    float* Q = (float*)d_ws;
    float* K = Q + (size_t)N_NODES * HID;
    float* V = K + (size_t)N_NODES * HID;
    float* S = V + (size_t)N_NODES * HID;
    float* alpha = S + (size_t)N_NODES * HID;             // [E,4]
    int* deg     = (int*)(alpha + (size_t)N_EDGES * HEADS);
    int* rowptr  = deg + N_NODES;                          // N+1
    int* fillctr = rowptr + (N_NODES + 1);
    int* csr_src = fillctr + N_NODES;
    int* csr_dst = csr_src + N_EDGES;

    hipMemsetAsync(deg, 0, N_NODES * sizeof(int), stream);
    hipMemsetAsync(fillctr, 0, N_NODES * sizeof(int), stream);

    const int row_tiles = (N_NODES + 63) / 64;          // 1563
    proj_gemm<<<row_tiles * 8, 256, 0, stream>>>(x, Wq, bq, Wk, bk, Wv, bv,
                                                 Ws, bs, Q, K, V, S);

    const int eblk = (N_EDGES + 255) / 256;             // 3125
    histo<<<eblk, 256, 0, stream>>>(ei, deg);
    scan_deg<<<1, 1024, 0, stream>>>(deg, rowptr);
    csr_fill<<<eblk, 256, 0, stream>>>(ei, rowptr, fillctr, csr_src, csr_dst);

    const int eblocks16 = (N_EDGES + 15) / 16;          // 50000
    edge_logits<<<eblocks16, 256, 0, stream>>>(csr_src, csr_dst, Q, K, alpha);

    node_gather<<<(N_NODES + 3) / 4, 256, 0, stream>>>(rowptr, csr_src, alpha,
                                                       V, S, gamma, beta, out);
}

// Round 3
// 413.440 us; speedup vs baseline: 7.9482x; 1.5918x over previous
//
#include <hip/hip_runtime.h>
#include <math.h>

#define N_NODES 100000
#define N_EDGES 800000
#define HID 128
#define HEADS 4
#define HD 32

typedef __attribute__((ext_vector_type(8))) short short8;
typedef __attribute__((ext_vector_type(4))) float f32x4;

__device__ __forceinline__ unsigned int f2bf(float f) {
    unsigned int u = __float_as_uint(f);
    u += 0x7FFFu + ((u >> 16) & 1u);
    return (u >> 16) & 0xFFFFu;   // RNE round to bf16
}

// ---------------------------------------------------------------------------
// Prep: W[k][n] fp32 -> Wt bf16 [m][n][kc] chunks of 8 k (transposed, linear).
// ---------------------------------------------------------------------------
__global__ __launch_bounds__(256) void conv_w(
    const float* __restrict__ Wq, const float* __restrict__ Wk,
    const float* __restrict__ Wv, const float* __restrict__ Ws,
    uint4* __restrict__ wtbf)
{
    int idx = blockIdx.x * 256 + threadIdx.x;       // [4][128][16]
    if (idx >= 4 * 128 * 16) return;
    int m = idx >> 11, n = (idx >> 4) & 127, kc = idx & 15;
    const float* W = (m == 0) ? Wq : (m == 1) ? Wk : (m == 2) ? Wv : Ws;
    unsigned int h[8];
    #pragma unroll
    for (int j = 0; j < 8; ++j) h[j] = f2bf(W[(kc * 8 + j) * HID + n]);
    uint4 o;
    o.x = h[0] | (h[1] << 16);
    o.y = h[2] | (h[3] << 16);
    o.z = h[4] | (h[5] << 16);
    o.w = h[6] | (h[7] << 16);
    wtbf[idx] = o;
}

// ---------------------------------------------------------------------------
// MFMA projections: block = 64 rows x 128 cols of one W matrix.
// LDS tiles XOR-swizzled (chunk ^= row&7) for conflict-free ds_read_b128.
// Epilogue bounces через LDS so global stores are coalesced float4.
// ---------------------------------------------------------------------------
__global__ __launch_bounds__(256) void proj_mfma(
    const float* __restrict__ x, const uint4* __restrict__ wtbf,
    const float* __restrict__ bq, const float* __restrict__ bk,
    const float* __restrict__ bv, const float* __restrict__ bs,
    float* __restrict__ Q, float* __restrict__ K,
    float* __restrict__ V, float* __restrict__ S)
{
    __shared__ uint4 smem[3072];        // 48 KB: xs[1024] | wt[2048]; reused fp32 in epilogue
    uint4* xs = smem;                   // 64 rows x 16 chunks (8 bf16 each)
    uint4* wt = smem + 1024;            // 128 n  x 16 chunks

    const int bid  = blockIdx.x;
    const int m    = bid & 3;
    const int rb   = (bid >> 2) * 64;
    const int tid  = threadIdx.x;
    const int lane = tid & 63;
    const int w    = tid >> 6;

    const float* bias = (m == 0) ? bq : (m == 1) ? bk : (m == 2) ? bv : bs;
    float*       outp = (m == 0) ? Q  : (m == 1) ? K  : (m == 2) ? V  : S;

    // stage x (fp32 -> bf16, swizzled)
    #pragma unroll
    for (int it = 0; it < 4; ++it) {
        int cid = it * 256 + tid;
        int row = cid >> 4, c = cid & 15;
        int grow = rb + row;
        float4 a = make_float4(0.f, 0.f, 0.f, 0.f);
        float4 b = make_float4(0.f, 0.f, 0.f, 0.f);
        if (grow < N_NODES) {
            const float4* p = (const float4*)(x + (size_t)grow * HID + c * 8);
            a = p[0]; b = p[1];
        }
        uint4 o;
        o.x = f2bf(a.x) | (f2bf(a.y) << 16);
        o.y = f2bf(a.z) | (f2bf(a.w) << 16);
        o.z = f2bf(b.x) | (f2bf(b.y) << 16);
        o.w = f2bf(b.z) | (f2bf(b.w) << 16);
        xs[row * 16 + (c ^ (row & 7))] = o;
    }
    // stage W (already bf16-transposed), swizzle on write
    const uint4* wsrc = wtbf + m * 2048;
    #pragma unroll
    for (int it = 0; it < 8; ++it) {
        int cid = it * 256 + tid;
        int n = cid >> 4, kc = cid & 15;
        wt[n * 16 + (kc ^ (n & 7))] = wsrc[cid];
    }
    __syncthreads();

    const int r  = lane & 15;   // A-row / B-col within 16-tile
    const int kg = lane >> 4;   // k-group of 8
    const int arow = w * 16 + r;

    short8 afr[4];
    #pragma unroll
    for (int s = 0; s < 4; ++s)
        afr[s] = *(const short8*)&xs[arow * 16 + ((s * 4 + kg) ^ (arow & 7))];

    f32x4 acc[8];
    #pragma unroll
    for (int nt = 0; nt < 8; ++nt) { acc[nt].x = 0.f; acc[nt].y = 0.f; acc[nt].z = 0.f; acc[nt].w = 0.f; }

    #pragma unroll
    for (int nt = 0; nt < 8; ++nt) {
        const int nrow = nt * 16 + r;
        #pragma unroll
        for (int s = 0; s < 4; ++s) {
            short8 bfr = *(const short8*)&wt[nrow * 16 + ((s * 4 + kg) ^ (nrow & 7))];
            acc[nt] = __builtin_amdgcn_mfma_f32_16x16x32_bf16(afr[s], bfr, acc[nt], 0, 0, 0);
        }
    }
    __syncthreads();   // all waves done reading tiles before LDS reuse

    // per-wave private epilogue region: 16 rows x 132 (pad) fp32
    float* ep = (float*)smem + w * 16 * 132;
    #pragma unroll
    for (int nt = 0; nt < 8; ++nt) {
        #pragma unroll
        for (int rr = 0; rr < 4; ++rr)
            ep[(kg * 4 + rr) * 132 + nt * 16 + r] = acc[nt][rr];
    }
    // no cross-wave sharing -> no barrier needed; coalesced float4 stores
    #pragma unroll
    for (int it = 0; it < 8; ++it) {
        int fid = it * 64 + lane;
        int rowl = fid >> 5, c4 = (fid & 31) * 4;
        int grow = rb + w * 16 + rowl;
        if (grow < N_NODES) {
            float4 v = *(const float4*)&ep[rowl * 132 + c4];
            float4 bi = *(const float4*)(bias + c4);
            float4 o;
            o.x = v.x + bi.x; o.y = v.y + bi.y;
            o.z = v.z + bi.z; o.w = v.w + bi.w;
            *(float4*)(outp + (size_t)grow * HID + c4) = o;
        }
    }
}

// ---------------------------------------------------------------------------
// CSR build: histogram of dst, exclusive scan, slot fill (src only).
// ---------------------------------------------------------------------------
__global__ __launch_bounds__(256) void histo(const int* __restrict__ ei,
                                             int* __restrict__ deg)
{
    int e = blockIdx.x * 256 + threadIdx.x;
    if (e < N_EDGES) atomicAdd(&deg[ei[N_EDGES + e]], 1);
}

__global__ __launch_bounds__(1024) void scan_deg(const int* __restrict__ deg,
                                                 int* __restrict__ rowptr)
{
    __shared__ int wsum[16];
    __shared__ int carry_sh;
    const int tid = threadIdx.x, lane = tid & 63, wid = tid >> 6;
    if (tid == 0) carry_sh = 0;
    __syncthreads();
    for (int base = 0; base < N_NODES; base += 1024) {
        int v = (base + tid < N_NODES) ? deg[base + tid] : 0;
        int x = v;
        #pragma unroll
        for (int off = 1; off < 64; off <<= 1) {
            int t = __shfl_up(x, off);
            if (lane >= off) x += t;
        }
        if (lane == 63) wsum[wid] = x;
        __syncthreads();
        int wpre = 0;
        #pragma unroll
        for (int wv = 0; wv < 15; ++wv) { if (wv < wid) wpre += wsum[wv]; }
        if (base + tid < N_NODES) rowptr[base + tid] = carry_sh + wpre + x - v;
        __syncthreads();
        if (tid == 1023) carry_sh += wpre + x;
        __syncthreads();
    }
    if (tid == 0) rowptr[N_NODES] = carry_sh;
}

__global__ __launch_bounds__(256) void csr_fill(const int* __restrict__ ei,
                                                const int* __restrict__ rowptr,
                                                int* __restrict__ fillctr,
                                                int* __restrict__ csr_src)
{
    int e = blockIdx.x * 256 + threadIdx.x;
    if (e >= N_EDGES) return;
    int src = ei[e], dst = ei[N_EDGES + e];
    int pos = rowptr[dst] + atomicAdd(&fillctr[dst], 1);
    csr_src[pos] = src;
}

// ---------------------------------------------------------------------------
// Fused per-node attention: online softmax over CSR edges + V gather
// + skip + LayerNorm. One wave per node, no atomics, no alpha array.
// ---------------------------------------------------------------------------
__global__ __launch_bounds__(256) void node_attn(
    const int* __restrict__ rowptr, const int* __restrict__ csr_src,
    const float* __restrict__ Q, const float* __restrict__ K,
    const float* __restrict__ V, const float* __restrict__ S,
    const float* __restrict__ gamma, const float* __restrict__ beta,
    float* __restrict__ out)
{
    const int tid  = threadIdx.x;
    const int lane = tid & 63;
    const int wid  = tid >> 6;
    const int node = blockIdx.x * 4 + wid;
    if (node >= N_NODES) return;

    const int j = lane * 2;                 // dims [j, j+1]; head = j/32 (16-lane groups)
    const int r0 = rowptr[node], r1 = rowptr[node + 1];

    float2 q2 = *(const float2*)(Q + (size_t)node * HID + j);

    float m = -INFINITY, den = 0.f, accx = 0.f, accy = 0.f;

    float2 k_n = make_float2(0.f, 0.f), v_n = make_float2(0.f, 0.f);
    if (r0 < r1) {
        int s0 = csr_src[r0];
        k_n = *(const float2*)(K + (size_t)s0 * HID + j);
        v_n = *(const float2*)(V + (size_t)s0 * HID + j);
    }
    for (int p = r0; p < r1; ++p) {
        float2 k2 = k_n, v2 = v_n;
        if (p + 1 < r1) {                   // prefetch next edge's K/V rows
            int sn = csr_src[p + 1];
            k_n = *(const float2*)(K + (size_t)sn * HID + j);
            v_n = *(const float2*)(V + (size_t)sn * HID + j);
        }
        float t = q2.x * k2.x + q2.y * k2.y;
        t += __shfl_xor(t, 1);
        t += __shfl_xor(t, 2);
        t += __shfl_xor(t, 4);
        t += __shfl_xor(t, 8);              // head-group (16 lanes) sum
        float a  = t * 0.1767766952966369f; // 1/sqrt(32)
        float mn = fmaxf(m, a);
        float sc = __expf(m - mn);          // first iter: exp(-inf)=0
        float e  = __expf(a - mn);
        den  = den  * sc + e;
        accx = accx * sc + e * v2.x;
        accy = accy * sc + e * v2.y;
        m = mn;
    }

    float inv = 1.0f / (den + 1e-16f);
    float2 s = *(const float2*)(S + (size_t)node * HID + j);
    float v0 = accx * inv + s.x;
    float v1 = accy * inv + s.y;

    float sum = v0 + v1;
    float sq  = v0 * v0 + v1 * v1;
    #pragma unroll
    for (int off = 1; off < 64; off <<= 1) {
        sum += __shfl_xor(sum, off);
        sq  += __shfl_xor(sq, off);
    }
    float mean = sum * (1.0f / 128.0f);
    float var  = sq * (1.0f / 128.0f) - mean * mean;
    float rstd = rsqrtf(var + 1e-5f);

    float2 g  = *(const float2*)(gamma + j);
    float2 bb = *(const float2*)(beta + j);
    float2 o;
    o.x = (v0 - mean) * rstd * g.x + bb.x;
    o.y = (v1 - mean) * rstd * g.y + bb.y;
    *(float2*)(out + (size_t)node * HID + j) = o;
}

// ---------------------------------------------------------------------------
extern "C" void kernel_launch(void* const* d_in, const int* in_sizes, int n_in,
                              void* d_out, int out_size, void* d_ws, size_t ws_size,
                              hipStream_t stream) {
    const float* x  = (const float*)d_in[0];
    const int*   ei = (const int*)d_in[1];
    const float* Wq = (const float*)d_in[2];
    const float* bq = (const float*)d_in[3];
    const float* Wk = (const float*)d_in[4];
    const float* bk = (const float*)d_in[5];
    const float* Wv = (const float*)d_in[6];
    const float* bv = (const float*)d_in[7];
    const float* Ws = (const float*)d_in[8];
    const float* bs = (const float*)d_in[9];
    const float* gamma = (const float*)d_in[10];
    const float* beta  = (const float*)d_in[11];
    float* out = (float*)d_out;

    // workspace layout
    float* Q = (float*)d_ws;
    float* K = Q + (size_t)N_NODES * HID;
    float* V = K + (size_t)N_NODES * HID;
    float* S = V + (size_t)N_NODES * HID;
    uint4* wtbf  = (uint4*)(S + (size_t)N_NODES * HID);   // [4*128*16]
    int* deg     = (int*)(wtbf + 4 * 128 * 16);
    int* rowptr  = deg + N_NODES;                          // N+1
    int* fillctr = rowptr + (N_NODES + 1);
    int* csr_src = fillctr + N_NODES;

    hipMemsetAsync(deg, 0, N_NODES * sizeof(int), stream);
    hipMemsetAsync(fillctr, 0, N_NODES * sizeof(int), stream);

    conv_w<<<32, 256, 0, stream>>>(Wq, Wk, Wv, Ws, wtbf);

    const int row_tiles = (N_NODES + 63) / 64;          // 1563
    proj_mfma<<<row_tiles * 4, 256, 0, stream>>>(x, wtbf, bq, bk, bv, bs,
                                                 Q, K, V, S);

    const int eblk = (N_EDGES + 255) / 256;             // 3125
    histo<<<eblk, 256, 0, stream>>>(ei, deg);
    scan_deg<<<1, 1024, 0, stream>>>(deg, rowptr);
    csr_fill<<<eblk, 256, 0, stream>>>(ei, rowptr, fillctr, csr_src);

    node_attn<<<(N_NODES + 3) / 4, 256, 0, stream>>>(rowptr, csr_src, Q, K, V, S,
                                                     gamma, beta, out);
}

// Round 4
// 269.226 us; speedup vs baseline: 12.2057x; 1.5357x over previous
//
#include <hip/hip_runtime.h>
#include <math.h>

#define N_NODES 100000
#define N_EDGES 800000
#define HID 128
#define HEADS 4
#define HD 32

typedef __attribute__((ext_vector_type(8))) short short8;
typedef __attribute__((ext_vector_type(4))) float f32x4;

__device__ __forceinline__ unsigned int f2bf(float f) {
    unsigned int u = __float_as_uint(f);
    u += 0x7FFFu + ((u >> 16) & 1u);
    return (u >> 16) & 0xFFFFu;   // RNE round to bf16
}
__device__ __forceinline__ float bf_lo(unsigned int u) { return __uint_as_float(u << 16); }
__device__ __forceinline__ float bf_hi(unsigned int u) { return __uint_as_float(u & 0xFFFF0000u); }

// ---------------------------------------------------------------------------
// Prep: W[k][n] fp32 -> Wt bf16 [m][n][kc] chunks of 8 k (transposed, linear).
// ---------------------------------------------------------------------------
__global__ __launch_bounds__(256) void conv_w(
    const float* __restrict__ Wq, const float* __restrict__ Wk,
    const float* __restrict__ Wv, const float* __restrict__ Ws,
    uint4* __restrict__ wtbf)
{
    int idx = blockIdx.x * 256 + threadIdx.x;       // [4][128][16]
    if (idx >= 4 * 128 * 16) return;
    int m = idx >> 11, n = (idx >> 4) & 127, kc = idx & 15;
    const float* W = (m == 0) ? Wq : (m == 1) ? Wk : (m == 2) ? Wv : Ws;
    unsigned int h[8];
    #pragma unroll
    for (int j = 0; j < 8; ++j) h[j] = f2bf(W[(kc * 8 + j) * HID + n]);
    uint4 o;
    o.x = h[0] | (h[1] << 16);
    o.y = h[2] | (h[3] << 16);
    o.z = h[4] | (h[5] << 16);
    o.w = h[6] | (h[7] << 16);
    wtbf[idx] = o;
}

// ---------------------------------------------------------------------------
// MFMA projections: one block = 64 rows x ALL 4 matrices (x staged once).
// Per-m W tile reloaded from L2-resident wtbf. Q,S out fp32; K,V out bf16.
// Epilogue bounces through the (dead) xs LDS region, two wave-phases.
// ---------------------------------------------------------------------------
__global__ __launch_bounds__(256) void proj_mfma(
    const float* __restrict__ x, const uint4* __restrict__ wtbf,
    const float* __restrict__ bq, const float* __restrict__ bk,
    const float* __restrict__ bv, const float* __restrict__ bs,
    float* __restrict__ Q, unsigned short* __restrict__ Kb,
    unsigned short* __restrict__ Vb, float* __restrict__ S)
{
    __shared__ uint4 smem[3072];        // 48 KB: xs[0..1023] | wt[1024..3071]
    uint4* xs = smem;                   // 64 rows x 16 chunks (8 bf16 each)
    uint4* wt = smem + 1024;            // 128 n  x 16 chunks
    float* epb = (float*)smem;          // epilogue overlaps xs (dead after afr load)

    const int rb   = blockIdx.x * 64;
    const int tid  = threadIdx.x;
    const int lane = tid & 63;
    const int w    = tid >> 6;

    // stage x (fp32 -> bf16, swizzled)
    #pragma unroll
    for (int it = 0; it < 4; ++it) {
        int cid = it * 256 + tid;
        int row = cid >> 4, c = cid & 15;
        int grow = rb + row;
        float4 a = make_float4(0.f, 0.f, 0.f, 0.f);
        float4 b = make_float4(0.f, 0.f, 0.f, 0.f);
        if (grow < N_NODES) {
            const float4* p = (const float4*)(x + (size_t)grow * HID + c * 8);
            a = p[0]; b = p[1];
        }
        uint4 o;
        o.x = f2bf(a.x) | (f2bf(a.y) << 16);
        o.y = f2bf(a.z) | (f2bf(a.w) << 16);
        o.z = f2bf(b.x) | (f2bf(b.y) << 16);
        o.w = f2bf(b.z) | (f2bf(b.w) << 16);
        xs[row * 16 + (c ^ (row & 7))] = o;
    }
    // stage W tile for m=0
    #pragma unroll
    for (int it = 0; it < 8; ++it) {
        int cid = it * 256 + tid;
        int n = cid >> 4, kc = cid & 15;
        wt[n * 16 + (kc ^ (n & 7))] = wtbf[cid];
    }
    __syncthreads();

    const int r  = lane & 15;
    const int kg = lane >> 4;
    const int arow = w * 16 + r;

    short8 afr[4];
    #pragma unroll
    for (int s = 0; s < 4; ++s)
        afr[s] = *(const short8*)&xs[arow * 16 + ((s * 4 + kg) ^ (arow & 7))];
    __syncthreads();   // all afr loaded before xs region is reused by epilogue

    float* epw = epb + (w & 1) * (16 * 66);

    for (int m = 0; m < 4; ++m) {
        f32x4 acc[8];
        #pragma unroll
        for (int nt = 0; nt < 8; ++nt) { acc[nt].x = 0.f; acc[nt].y = 0.f; acc[nt].z = 0.f; acc[nt].w = 0.f; }
        #pragma unroll
        for (int nt = 0; nt < 8; ++nt) {
            const int nrow = nt * 16 + r;
            #pragma unroll
            for (int s = 0; s < 4; ++s) {
                short8 bfr = *(const short8*)&wt[nrow * 16 + ((s * 4 + kg) ^ (nrow & 7))];
                acc[nt] = __builtin_amdgcn_mfma_f32_16x16x32_bf16(afr[s], bfr, acc[nt], 0, 0, 0);
            }
        }

        const float* bias = (m == 0) ? bq : (m == 1) ? bk : (m == 2) ? bv : bs;

        // two-phase epilogue: waves {0,1} then {2,3} through shared 8.5KB region
        #pragma unroll
        for (int phase = 0; phase < 2; ++phase) {
            if (phase == 1) {
                // (phase==0 half done) barrier, then other half + wt restage overlap
            }
            bool active = (phase == 0) ? (w < 2) : (w >= 2);
            if (phase == 1) { /* placeholder to keep structure flat */ }
            if (active) {
                #pragma unroll
                for (int h = 0; h < 2; ++h) {
                    #pragma unroll
                    for (int nt2 = 0; nt2 < 4; ++nt2) {
                        int nt = h * 4 + nt2;
                        #pragma unroll
                        for (int rr = 0; rr < 4; ++rr)
                            epw[(kg * 4 + rr) * 66 + nt2 * 16 + r] = acc[nt][rr];
                    }
                    #pragma unroll
                    for (int it = 0; it < 4; ++it) {
                        int fid = it * 64 + lane;
                        int rowl = fid >> 4, c4 = (fid & 15) * 4;
                        int grow = rb + w * 16 + rowl;
                        if (grow < N_NODES) {
                            float4 v = *(const float4*)&epw[rowl * 66 + c4];
                            int col = h * 64 + c4;
                            float4 bi = *(const float4*)(bias + col);
                            v.x += bi.x; v.y += bi.y; v.z += bi.z; v.w += bi.w;
                            if (m == 0) {
                                *(float4*)(Q + (size_t)grow * HID + col) = v;
                            } else if (m == 3) {
                                *(float4*)(S + (size_t)grow * HID + col) = v;
                            } else {
                                uint2 pk;
                                pk.x = f2bf(v.x) | (f2bf(v.y) << 16);
                                pk.y = f2bf(v.z) | (f2bf(v.w) << 16);
                                unsigned short* ob = (m == 1) ? Kb : Vb;
                                *(uint2*)(ob + (size_t)grow * HID + col) = pk;
                            }
                        }
                    }
                }
            }
            if (phase == 0) __syncthreads();
        }
        if (m < 3) {
            const uint4* wsrc = wtbf + (m + 1) * 2048;
            #pragma unroll
            for (int it = 0; it < 8; ++it) {
                int cid = it * 256 + tid;
                int n = cid >> 4, kc = cid & 15;
                wt[n * 16 + (kc ^ (n & 7))] = wsrc[cid];
            }
            __syncthreads();
        }
    }
}

// ---------------------------------------------------------------------------
// CSR build: histogram, hierarchical scan (49 blk -> 1 wave -> add), fill.
// ---------------------------------------------------------------------------
__global__ __launch_bounds__(256) void histo(const int* __restrict__ ei,
                                             int* __restrict__ deg)
{
    int e = blockIdx.x * 256 + threadIdx.x;
    if (e < N_EDGES) atomicAdd(&deg[ei[N_EDGES + e]], 1);
}

__global__ __launch_bounds__(256) void scan_local(const int* __restrict__ deg,
                                                  int* __restrict__ rowptr,
                                                  int* __restrict__ bsum)
{
    __shared__ int wsums[4];
    const int b = blockIdx.x, t = threadIdx.x, lane = t & 63, wid = t >> 6;
    const int base = b * 2048 + t * 8;
    int v[8], s = 0;
    #pragma unroll
    for (int j = 0; j < 8; ++j) {
        int i = base + j;
        v[j] = (i < N_NODES) ? deg[i] : 0;
        s += v[j];
    }
    const int tsum = s;
    int x = tsum;
    #pragma unroll
    for (int off = 1; off < 64; off <<= 1) {
        int t2 = __shfl_up(x, off);
        if (lane >= off) x += t2;
    }
    if (lane == 63) wsums[wid] = x;
    __syncthreads();
    int wpre = 0;
    #pragma unroll
    for (int ww = 0; ww < 4; ++ww) { if (ww < wid) wpre += wsums[ww]; }
    int run = wpre + x - tsum;
    #pragma unroll
    for (int j = 0; j < 8; ++j) {
        int i = base + j;
        if (i < N_NODES) rowptr[i] = run;
        run += v[j];
    }
    if (t == 0) bsum[b] = wsums[0] + wsums[1] + wsums[2] + wsums[3];
}

__global__ __launch_bounds__(64) void scan_bsum(int* __restrict__ bsum,
                                                int* __restrict__ rowptr,
                                                int nb)
{
    const int lane = threadIdx.x;
    int v = (lane < nb) ? bsum[lane] : 0;
    int x = v;
    #pragma unroll
    for (int off = 1; off < 64; off <<= 1) {
        int t2 = __shfl_up(x, off);
        if (lane >= off) x += t2;
    }
    if (lane < nb) bsum[lane] = x - v;     // exclusive
    if (lane == 63) rowptr[N_NODES] = x;   // grand total
}

__global__ __launch_bounds__(256) void add_off(int* __restrict__ rowptr,
                                               const int* __restrict__ bsum)
{
    int i = blockIdx.x * 256 + threadIdx.x;
    if (i < N_NODES) rowptr[i] += bsum[i >> 11];
}

__global__ __launch_bounds__(256) void csr_fill(const int* __restrict__ ei,
                                                const int* __restrict__ rowptr,
                                                int* __restrict__ fillctr,
                                                int* __restrict__ csr_src)
{
    int e = blockIdx.x * 256 + threadIdx.x;
    if (e >= N_EDGES) return;
    int src = ei[e], dst = ei[N_EDGES + e];
    int pos = rowptr[dst] + atomicAdd(&fillctr[dst], 1);
    csr_src[pos] = src;
}

// ---------------------------------------------------------------------------
// Fused per-node attention: online softmax (2-edge unrolled) over CSR edges,
// bf16 K/V gather, skip + LayerNorm. One wave per node, no atomics.
// ---------------------------------------------------------------------------
__global__ __launch_bounds__(256) void node_attn(
    const int* __restrict__ rowptr, const int* __restrict__ csr_src,
    const float* __restrict__ Q, const unsigned short* __restrict__ Kb,
    const unsigned short* __restrict__ Vb, const float* __restrict__ S,
    const float* __restrict__ gamma, const float* __restrict__ beta,
    float* __restrict__ out)
{
    const int tid  = threadIdx.x;
    const int lane = tid & 63;
    const int wid  = tid >> 6;
    const int node = blockIdx.x * 4 + wid;
    if (node >= N_NODES) return;

    const int j = lane * 2;                 // dims [j, j+1]; head = j/32
    const int r0 = rowptr[node], r1 = rowptr[node + 1];

    float2 q2 = *(const float2*)(Q + (size_t)node * HID + j);

    float m = -INFINITY, den = 0.f, ax = 0.f, ay = 0.f;

    unsigned int k0 = 0, v0 = 0, k1 = 0, v1 = 0;
    bool has1 = (r0 + 1 < r1);
    if (r0 < r1) {
        int s0 = csr_src[r0];
        k0 = *(const unsigned int*)(Kb + (size_t)s0 * HID + j);
        v0 = *(const unsigned int*)(Vb + (size_t)s0 * HID + j);
    }
    if (has1) {
        int s1 = csr_src[r0 + 1];
        k1 = *(const unsigned int*)(Kb + (size_t)s1 * HID + j);
        v1 = *(const unsigned int*)(Vb + (size_t)s1 * HID + j);
    }

    for (int p = r0; p < r1; p += 2) {
        // prefetch next pair
        unsigned int k0n = 0, v0n = 0, k1n = 0, v1n = 0;
        const int np = p + 2;
        const bool nh0 = np < r1, nh1 = np + 1 < r1;
        if (nh0) {
            int sn = csr_src[np];
            k0n = *(const unsigned int*)(Kb + (size_t)sn * HID + j);
            v0n = *(const unsigned int*)(Vb + (size_t)sn * HID + j);
        }
        if (nh1) {
            int sn = csr_src[np + 1];
            k1n = *(const unsigned int*)(Kb + (size_t)sn * HID + j);
            v1n = *(const unsigned int*)(Vb + (size_t)sn * HID + j);
        }

        // two independent dot+reduce chains
        float t0 = q2.x * bf_lo(k0) + q2.y * bf_hi(k0);
        float t1 = q2.x * bf_lo(k1) + q2.y * bf_hi(k1);
        t0 += __shfl_xor(t0, 1);  t1 += __shfl_xor(t1, 1);
        t0 += __shfl_xor(t0, 2);  t1 += __shfl_xor(t1, 2);
        t0 += __shfl_xor(t0, 4);  t1 += __shfl_xor(t1, 4);
        t0 += __shfl_xor(t0, 8);  t1 += __shfl_xor(t1, 8);
        float a0 = t0 * 0.1767766952966369f;            // 1/sqrt(32)
        float a1 = has1 ? (t1 * 0.1767766952966369f) : -INFINITY;

        float mn = fmaxf(m, fmaxf(a0, a1));
        float sc = __expf(m - mn);                      // first iter: 0
        float e0 = __expf(a0 - mn);
        float e1 = has1 ? __expf(a1 - mn) : 0.f;
        den = den * sc + e0 + e1;
        ax  = ax  * sc + e0 * bf_lo(v0) + e1 * bf_lo(v1);
        ay  = ay  * sc + e0 * bf_hi(v0) + e1 * bf_hi(v1);
        m = mn;

        k0 = k0n; v0 = v0n; k1 = k1n; v1 = v1n; has1 = nh1;
    }

    float inv = 1.0f / (den + 1e-16f);
    float2 s = *(const float2*)(S + (size_t)node * HID + j);
    float o0 = ax * inv + s.x;
    float o1 = ay * inv + s.y;

    float sum = o0 + o1;
    float sq  = o0 * o0 + o1 * o1;
    #pragma unroll
    for (int off = 1; off < 64; off <<= 1) {
        sum += __shfl_xor(sum, off);
        sq  += __shfl_xor(sq, off);
    }
    float mean = sum * (1.0f / 128.0f);
    float var  = sq * (1.0f / 128.0f) - mean * mean;
    float rstd = rsqrtf(var + 1e-5f);

    float2 g  = *(const float2*)(gamma + j);
    float2 bb = *(const float2*)(beta + j);
    float2 o;
    o.x = (o0 - mean) * rstd * g.x + bb.x;
    o.y = (o1 - mean) * rstd * g.y + bb.y;
    *(float2*)(out + (size_t)node * HID + j) = o;
}

// ---------------------------------------------------------------------------
extern "C" void kernel_launch(void* const* d_in, const int* in_sizes, int n_in,
                              void* d_out, int out_size, void* d_ws, size_t ws_size,
                              hipStream_t stream) {
    const float* x  = (const float*)d_in[0];
    const int*   ei = (const int*)d_in[1];
    const float* Wq = (const float*)d_in[2];
    const float* bq = (const float*)d_in[3];
    const float* Wk = (const float*)d_in[4];
    const float* bk = (const float*)d_in[5];
    const float* Wv = (const float*)d_in[6];
    const float* bv = (const float*)d_in[7];
    const float* Ws = (const float*)d_in[8];
    const float* bs = (const float*)d_in[9];
    const float* gamma = (const float*)d_in[10];
    const float* beta  = (const float*)d_in[11];
    float* out = (float*)d_out;

    // workspace layout
    float* Q = (float*)d_ws;                               // [N,128] fp32
    float* S = Q + (size_t)N_NODES * HID;                  // [N,128] fp32
    unsigned short* Kb = (unsigned short*)(S + (size_t)N_NODES * HID);  // [N,128] bf16
    unsigned short* Vb = Kb + (size_t)N_NODES * HID;
    uint4* wtbf  = (uint4*)(Vb + (size_t)N_NODES * HID);   // [4*128*16]
    int* deg     = (int*)(wtbf + 4 * 128 * 16);
    int* rowptr  = deg + N_NODES;                          // N+1
    int* fillctr = rowptr + (N_NODES + 1);
    int* csr_src = fillctr + N_NODES;
    int* bsum    = csr_src + N_EDGES;                      // 64

    hipMemsetAsync(deg, 0, N_NODES * sizeof(int), stream);
    hipMemsetAsync(fillctr, 0, N_NODES * sizeof(int), stream);

    conv_w<<<32, 256, 0, stream>>>(Wq, Wk, Wv, Ws, wtbf);

    const int row_tiles = (N_NODES + 63) / 64;             // 1563
    proj_mfma<<<row_tiles, 256, 0, stream>>>(x, wtbf, bq, bk, bv, bs,
                                             Q, Kb, Vb, S);

    const int eblk = (N_EDGES + 255) / 256;                // 3125
    histo<<<eblk, 256, 0, stream>>>(ei, deg);
    const int nb = (N_NODES + 2047) / 2048;                // 49
    scan_local<<<nb, 256, 0, stream>>>(deg, rowptr, bsum);
    scan_bsum<<<1, 64, 0, stream>>>(bsum, rowptr, nb);
    add_off<<<(N_NODES + 255) / 256, 256, 0, stream>>>(rowptr, bsum);
    csr_fill<<<eblk, 256, 0, stream>>>(ei, rowptr, fillctr, csr_src);

    node_attn<<<(N_NODES + 3) / 4, 256, 0, stream>>>(rowptr, csr_src, Q, Kb, Vb, S,
                                                     gamma, beta, out);
}

// Round 5
// 255.439 us; speedup vs baseline: 12.8645x; 1.0540x over previous
//
#include <hip/hip_runtime.h>
#include <math.h>

#define N_NODES 100000
#define N_EDGES 800000
#define HID 128
#define HEADS 4
#define HD 32

typedef __attribute__((ext_vector_type(8))) short short8;
typedef __attribute__((ext_vector_type(4))) float f32x4;

__device__ __forceinline__ unsigned int f2bf(float f) {
    unsigned int u = __float_as_uint(f);
    u += 0x7FFFu + ((u >> 16) & 1u);
    return (u >> 16) & 0xFFFFu;   // RNE round to bf16
}
__device__ __forceinline__ float bf_lo(unsigned int u) { return __uint_as_float(u << 16); }
__device__ __forceinline__ float bf_hi(unsigned int u) { return __uint_as_float(u & 0xFFFF0000u); }

// ---------------------------------------------------------------------------
// Prep: W[k][n] fp32 -> Wt bf16 [m][n][kc] chunks of 8 k (transposed, linear).
// ---------------------------------------------------------------------------
__global__ __launch_bounds__(256) void conv_w(
    const float* __restrict__ Wq, const float* __restrict__ Wk,
    const float* __restrict__ Wv, const float* __restrict__ Ws,
    uint4* __restrict__ wtbf)
{
    int idx = blockIdx.x * 256 + threadIdx.x;       // [4][128][16]
    if (idx >= 4 * 128 * 16) return;
    int m = idx >> 11, n = (idx >> 4) & 127, kc = idx & 15;
    const float* W = (m == 0) ? Wq : (m == 1) ? Wk : (m == 2) ? Wv : Ws;
    unsigned int h[8];
    #pragma unroll
    for (int j = 0; j < 8; ++j) h[j] = f2bf(W[(kc * 8 + j) * HID + n]);
    uint4 o;
    o.x = h[0] | (h[1] << 16);
    o.y = h[2] | (h[3] << 16);
    o.z = h[4] | (h[5] << 16);
    o.w = h[6] | (h[7] << 16);
    wtbf[idx] = o;
}

// ---------------------------------------------------------------------------
// MFMA projections: one block = 64 rows x ALL 4 matrices (x staged once).
// Per-m W tile reloaded from L2-resident wtbf. Q,S out fp32; K,V out bf16.
// Epilogue bounces through the (dead) xs LDS region, two wave-phases.
// ---------------------------------------------------------------------------
__global__ __launch_bounds__(256) void proj_mfma(
    const float* __restrict__ x, const uint4* __restrict__ wtbf,
    const float* __restrict__ bq, const float* __restrict__ bk,
    const float* __restrict__ bv, const float* __restrict__ bs,
    float* __restrict__ Q, unsigned short* __restrict__ Kb,
    unsigned short* __restrict__ Vb, float* __restrict__ S)
{
    __shared__ uint4 smem[3072];        // 48 KB: xs[0..1023] | wt[1024..3071]
    uint4* xs = smem;                   // 64 rows x 16 chunks (8 bf16 each)
    uint4* wt = smem + 1024;            // 128 n  x 16 chunks
    float* epb = (float*)smem;          // epilogue overlaps xs (dead after afr load)

    const int rb   = blockIdx.x * 64;
    const int tid  = threadIdx.x;
    const int lane = tid & 63;
    const int w    = tid >> 6;

    // stage x (fp32 -> bf16, swizzled)
    #pragma unroll
    for (int it = 0; it < 4; ++it) {
        int cid = it * 256 + tid;
        int row = cid >> 4, c = cid & 15;
        int grow = rb + row;
        float4 a = make_float4(0.f, 0.f, 0.f, 0.f);
        float4 b = make_float4(0.f, 0.f, 0.f, 0.f);
        if (grow < N_NODES) {
            const float4* p = (const float4*)(x + (size_t)grow * HID + c * 8);
            a = p[0]; b = p[1];
        }
        uint4 o;
        o.x = f2bf(a.x) | (f2bf(a.y) << 16);
        o.y = f2bf(a.z) | (f2bf(a.w) << 16);
        o.z = f2bf(b.x) | (f2bf(b.y) << 16);
        o.w = f2bf(b.z) | (f2bf(b.w) << 16);
        xs[row * 16 + (c ^ (row & 7))] = o;
    }
    // stage W tile for m=0
    #pragma unroll
    for (int it = 0; it < 8; ++it) {
        int cid = it * 256 + tid;
        int n = cid >> 4, kc = cid & 15;
        wt[n * 16 + (kc ^ (n & 7))] = wtbf[cid];
    }
    __syncthreads();

    const int r  = lane & 15;
    const int kg = lane >> 4;
    const int arow = w * 16 + r;

    short8 afr[4];
    #pragma unroll
    for (int s = 0; s < 4; ++s)
        afr[s] = *(const short8*)&xs[arow * 16 + ((s * 4 + kg) ^ (arow & 7))];
    __syncthreads();   // all afr loaded before xs region is reused by epilogue

    float* epw = epb + (w & 1) * (16 * 66);

    for (int m = 0; m < 4; ++m) {
        f32x4 acc[8];
        #pragma unroll
        for (int nt = 0; nt < 8; ++nt) { acc[nt].x = 0.f; acc[nt].y = 0.f; acc[nt].z = 0.f; acc[nt].w = 0.f; }
        #pragma unroll
        for (int nt = 0; nt < 8; ++nt) {
            const int nrow = nt * 16 + r;
            #pragma unroll
            for (int s = 0; s < 4; ++s) {
                short8 bfr = *(const short8*)&wt[nrow * 16 + ((s * 4 + kg) ^ (nrow & 7))];
                acc[nt] = __builtin_amdgcn_mfma_f32_16x16x32_bf16(afr[s], bfr, acc[nt], 0, 0, 0);
            }
        }

        const float* bias = (m == 0) ? bq : (m == 1) ? bk : (m == 2) ? bv : bs;

        // two-phase epilogue: waves {0,1} then {2,3} through shared 8.5KB region
        #pragma unroll
        for (int phase = 0; phase < 2; ++phase) {
            bool active = (phase == 0) ? (w < 2) : (w >= 2);
            if (active) {
                #pragma unroll
                for (int h = 0; h < 2; ++h) {
                    #pragma unroll
                    for (int nt2 = 0; nt2 < 4; ++nt2) {
                        int nt = h * 4 + nt2;
                        #pragma unroll
                        for (int rr = 0; rr < 4; ++rr)
                            epw[(kg * 4 + rr) * 66 + nt2 * 16 + r] = acc[nt][rr];
                    }
                    #pragma unroll
                    for (int it = 0; it < 4; ++it) {
                        int fid = it * 64 + lane;
                        int rowl = fid >> 4, c4 = (fid & 15) * 4;
                        int grow = rb + w * 16 + rowl;
                        if (grow < N_NODES) {
                            float4 v = *(const float4*)&epw[rowl * 66 + c4];
                            int col = h * 64 + c4;
                            float4 bi = *(const float4*)(bias + col);
                            v.x += bi.x; v.y += bi.y; v.z += bi.z; v.w += bi.w;
                            if (m == 0) {
                                *(float4*)(Q + (size_t)grow * HID + col) = v;
                            } else if (m == 3) {
                                *(float4*)(S + (size_t)grow * HID + col) = v;
                            } else {
                                uint2 pk;
                                pk.x = f2bf(v.x) | (f2bf(v.y) << 16);
                                pk.y = f2bf(v.z) | (f2bf(v.w) << 16);
                                unsigned short* ob = (m == 1) ? Kb : Vb;
                                *(uint2*)(ob + (size_t)grow * HID + col) = pk;
                            }
                        }
                    }
                }
            }
            if (phase == 0) __syncthreads();
        }
        if (m < 3) {
            const uint4* wsrc = wtbf + (m + 1) * 2048;
            #pragma unroll
            for (int it = 0; it < 8; ++it) {
                int cid = it * 256 + tid;
                int n = cid >> 4, kc = cid & 15;
                wt[n * 16 + (kc ^ (n & 7))] = wsrc[cid];
            }
            __syncthreads();
        }
    }
}

// ---------------------------------------------------------------------------
// CSR build: histogram, hierarchical scan (49 blk -> 1 wave -> add), fill.
// ---------------------------------------------------------------------------
__global__ __launch_bounds__(256) void histo(const int* __restrict__ ei,
                                             int* __restrict__ deg)
{
    int e = blockIdx.x * 256 + threadIdx.x;
    if (e < N_EDGES) atomicAdd(&deg[ei[N_EDGES + e]], 1);
}

__global__ __launch_bounds__(256) void scan_local(const int* __restrict__ deg,
                                                  int* __restrict__ rowptr,
                                                  int* __restrict__ bsum)
{
    __shared__ int wsums[4];
    const int b = blockIdx.x, t = threadIdx.x, lane = t & 63, wid = t >> 6;
    const int base = b * 2048 + t * 8;
    int v[8], s = 0;
    #pragma unroll
    for (int j = 0; j < 8; ++j) {
        int i = base + j;
        v[j] = (i < N_NODES) ? deg[i] : 0;
        s += v[j];
    }
    const int tsum = s;
    int x = tsum;
    #pragma unroll
    for (int off = 1; off < 64; off <<= 1) {
        int t2 = __shfl_up(x, off);
        if (lane >= off) x += t2;
    }
    if (lane == 63) wsums[wid] = x;
    __syncthreads();
    int wpre = 0;
    #pragma unroll
    for (int ww = 0; ww < 4; ++ww) { if (ww < wid) wpre += wsums[ww]; }
    int run = wpre + x - tsum;
    #pragma unroll
    for (int j = 0; j < 8; ++j) {
        int i = base + j;
        if (i < N_NODES) rowptr[i] = run;
        run += v[j];
    }
    if (t == 0) bsum[b] = wsums[0] + wsums[1] + wsums[2] + wsums[3];
}

__global__ __launch_bounds__(64) void scan_bsum(int* __restrict__ bsum,
                                                int* __restrict__ rowptr,
                                                int nb)
{
    const int lane = threadIdx.x;
    int v = (lane < nb) ? bsum[lane] : 0;
    int x = v;
    #pragma unroll
    for (int off = 1; off < 64; off <<= 1) {
        int t2 = __shfl_up(x, off);
        if (lane >= off) x += t2;
    }
    if (lane < nb) bsum[lane] = x - v;     // exclusive
    if (lane == 63) rowptr[N_NODES] = x;   // grand total
}

__global__ __launch_bounds__(256) void add_off(int* __restrict__ rowptr,
                                               const int* __restrict__ bsum)
{
    int i = blockIdx.x * 256 + threadIdx.x;
    if (i < N_NODES) rowptr[i] += bsum[i >> 11];
}

__global__ __launch_bounds__(256) void csr_fill(const int* __restrict__ ei,
                                                const int* __restrict__ rowptr,
                                                int* __restrict__ fillctr,
                                                int* __restrict__ csr_src)
{
    int e = blockIdx.x * 256 + threadIdx.x;
    if (e >= N_EDGES) return;
    int src = ei[e], dst = ei[N_EDGES + e];
    int pos = rowptr[dst] + atomicAdd(&fillctr[dst], 1);
    csr_src[pos] = src;
}

// ---------------------------------------------------------------------------
// Fused per-node attention: one wave per node; two 32-lane halves process
// independent edge streams (even/odd CSR slots), 8 lanes per head-dot
// (3 shuffle levels), 2-edge unroll per half. Online softmax states merged
// across halves at the end. bf16 K/V gather; skip + LayerNorm fused.
// ---------------------------------------------------------------------------
__global__ __launch_bounds__(256) void node_attn(
    const int* __restrict__ rowptr, const int* __restrict__ csr_src,
    const float* __restrict__ Q, const unsigned short* __restrict__ Kb,
    const unsigned short* __restrict__ Vb, const float* __restrict__ S,
    const float* __restrict__ gamma, const float* __restrict__ beta,
    float* __restrict__ out)
{
    const int tid  = threadIdx.x;
    const int lane = tid & 63;
    const int wid  = tid >> 6;
    const int node = blockIdx.x * 4 + wid;
    if (node >= N_NODES) return;

    const int half = lane >> 5;
    const int l5   = lane & 31;
    const int j    = l5 * 4;               // dims j..j+3; head = l5>>3

    const int r0 = rowptr[node], r1 = rowptr[node + 1];

    float4 q4 = *(const float4*)(Q + (size_t)node * HID + j);

    float m = -INFINITY, den = 0.f;
    float ax = 0.f, ay = 0.f, az = 0.f, aw = 0.f;

    int p0 = r0 + half;
    int p1 = p0 + 2;
    bool h0 = p0 < r1, h1 = p1 < r1;

    uint2 k0 = {0,0}, v0 = {0,0}, k1 = {0,0}, v1 = {0,0};
    if (h0) { int s = csr_src[p0];
        k0 = *(const uint2*)(Kb + (size_t)s * HID + j);
        v0 = *(const uint2*)(Vb + (size_t)s * HID + j); }
    if (h1) { int s = csr_src[p1];
        k1 = *(const uint2*)(Kb + (size_t)s * HID + j);
        v1 = *(const uint2*)(Vb + (size_t)s * HID + j); }

    while (h0) {
        const int np0 = p0 + 4, np1 = p1 + 4;
        const bool nh0 = np0 < r1, nh1 = np1 < r1;
        uint2 k0n = {0,0}, v0n = {0,0}, k1n = {0,0}, v1n = {0,0};
        if (nh0) { int s = csr_src[np0];
            k0n = *(const uint2*)(Kb + (size_t)s * HID + j);
            v0n = *(const uint2*)(Vb + (size_t)s * HID + j); }
        if (nh1) { int s = csr_src[np1];
            k1n = *(const uint2*)(Kb + (size_t)s * HID + j);
            v1n = *(const uint2*)(Vb + (size_t)s * HID + j); }

        // two independent dot chains (each shfl serves both halves)
        float t0 = q4.x * bf_lo(k0.x) + q4.y * bf_hi(k0.x)
                 + q4.z * bf_lo(k0.y) + q4.w * bf_hi(k0.y);
        float t1 = q4.x * bf_lo(k1.x) + q4.y * bf_hi(k1.x)
                 + q4.z * bf_lo(k1.y) + q4.w * bf_hi(k1.y);
        t0 += __shfl_xor(t0, 1);  t1 += __shfl_xor(t1, 1);
        t0 += __shfl_xor(t0, 2);  t1 += __shfl_xor(t1, 2);
        t0 += __shfl_xor(t0, 4);  t1 += __shfl_xor(t1, 4);
        float a0 = t0 * 0.1767766952966369f;              // 1/sqrt(32)
        float a1 = h1 ? (t1 * 0.1767766952966369f) : -INFINITY;

        float mn = fmaxf(m, fmaxf(a0, a1));
        float sc = __expf(m - mn);                        // first iter: 0
        float e0 = __expf(a0 - mn);
        float e1 = h1 ? __expf(a1 - mn) : 0.f;
        den = den * sc + e0 + e1;
        ax = ax * sc + e0 * bf_lo(v0.x) + e1 * bf_lo(v1.x);
        ay = ay * sc + e0 * bf_hi(v0.x) + e1 * bf_hi(v1.x);
        az = az * sc + e0 * bf_lo(v0.y) + e1 * bf_lo(v1.y);
        aw = aw * sc + e0 * bf_hi(v0.y) + e1 * bf_hi(v1.y);
        m = mn;

        p0 = np0; p1 = np1; h0 = nh0; h1 = nh1;
        k0 = k0n; v0 = v0n; k1 = k1n; v1 = v1n;
    }

    // merge the two halves' online-softmax states (lanes l <-> l^32)
    float m_o   = __shfl_xor(m, 32);
    float den_o = __shfl_xor(den, 32);
    float ax_o = __shfl_xor(ax, 32);
    float ay_o = __shfl_xor(ay, 32);
    float az_o = __shfl_xor(az, 32);
    float aw_o = __shfl_xor(aw, 32);
    float mm  = fmaxf(m, m_o);
    float scs = (m   > -INFINITY) ? __expf(m   - mm) : 0.f;
    float sco = (m_o > -INFINITY) ? __expf(m_o - mm) : 0.f;
    float dent = den * scs + den_o * sco;
    float fx = ax * scs + ax_o * sco;
    float fy = ay * scs + ay_o * sco;
    float fz = az * scs + az_o * sco;
    float fw = aw * scs + aw_o * sco;

    float inv = 1.0f / (dent + 1e-16f);
    float4 s4 = *(const float4*)(S + (size_t)node * HID + j);
    float o0 = fx * inv + s4.x;
    float o1 = fy * inv + s4.y;
    float o2 = fz * inv + s4.z;
    float o3 = fw * inv + s4.w;

    // LayerNorm: reduce within each 32-lane half (both halves identical)
    float sum = o0 + o1 + o2 + o3;
    float sq  = o0 * o0 + o1 * o1 + o2 * o2 + o3 * o3;
    #pragma unroll
    for (int off = 1; off < 32; off <<= 1) {
        sum += __shfl_xor(sum, off);
        sq  += __shfl_xor(sq, off);
    }
    float mean = sum * (1.0f / 128.0f);
    float var  = sq * (1.0f / 128.0f) - mean * mean;
    float rstd = rsqrtf(var + 1e-5f);

    if (half == 0) {
        float4 g  = *(const float4*)(gamma + j);
        float4 bb = *(const float4*)(beta + j);
        float4 o;
        o.x = (o0 - mean) * rstd * g.x + bb.x;
        o.y = (o1 - mean) * rstd * g.y + bb.y;
        o.z = (o2 - mean) * rstd * g.z + bb.z;
        o.w = (o3 - mean) * rstd * g.w + bb.w;
        *(float4*)(out + (size_t)node * HID + j) = o;
    }
}

// ---------------------------------------------------------------------------
extern "C" void kernel_launch(void* const* d_in, const int* in_sizes, int n_in,
                              void* d_out, int out_size, void* d_ws, size_t ws_size,
                              hipStream_t stream) {
    const float* x  = (const float*)d_in[0];
    const int*   ei = (const int*)d_in[1];
    const float* Wq = (const float*)d_in[2];
    const float* bq = (const float*)d_in[3];
    const float* Wk = (const float*)d_in[4];
    const float* bk = (const float*)d_in[5];
    const float* Wv = (const float*)d_in[6];
    const float* bv = (const float*)d_in[7];
    const float* Ws = (const float*)d_in[8];
    const float* bs = (const float*)d_in[9];
    const float* gamma = (const float*)d_in[10];
    const float* beta  = (const float*)d_in[11];
    float* out = (float*)d_out;

    // workspace layout
    float* Q = (float*)d_ws;                               // [N,128] fp32
    float* S = Q + (size_t)N_NODES * HID;                  // [N,128] fp32
    unsigned short* Kb = (unsigned short*)(S + (size_t)N_NODES * HID);  // [N,128] bf16
    unsigned short* Vb = Kb + (size_t)N_NODES * HID;
    uint4* wtbf  = (uint4*)(Vb + (size_t)N_NODES * HID);   // [4*128*16]
    int* deg     = (int*)(wtbf + 4 * 128 * 16);
    int* rowptr  = deg + N_NODES;                          // N+1
    int* fillctr = rowptr + (N_NODES + 1);
    int* csr_src = fillctr + N_NODES;
    int* bsum    = csr_src + N_EDGES;                      // 64

    hipMemsetAsync(deg, 0, N_NODES * sizeof(int), stream);
    hipMemsetAsync(fillctr, 0, N_NODES * sizeof(int), stream);

    conv_w<<<32, 256, 0, stream>>>(Wq, Wk, Wv, Ws, wtbf);

    const int row_tiles = (N_NODES + 63) / 64;             // 1563
    proj_mfma<<<row_tiles, 256, 0, stream>>>(x, wtbf, bq, bk, bv, bs,
                                             Q, Kb, Vb, S);

    const int eblk = (N_EDGES + 255) / 256;                // 3125
    histo<<<eblk, 256, 0, stream>>>(ei, deg);
    const int nb = (N_NODES + 2047) / 2048;                // 49
    scan_local<<<nb, 256, 0, stream>>>(deg, rowptr, bsum);
    scan_bsum<<<1, 64, 0, stream>>>(bsum, rowptr, nb);
    add_off<<<(N_NODES + 255) / 256, 256, 0, stream>>>(rowptr, bsum);
    csr_fill<<<eblk, 256, 0, stream>>>(ei, rowptr, fillctr, csr_src);

    node_attn<<<(N_NODES + 3) / 4, 256, 0, stream>>>(rowptr, csr_src, Q, Kb, Vb, S,
                                                     gamma, beta, out);
}

// Round 7
// 249.461 us; speedup vs baseline: 13.1728x; 1.0240x over previous
//
#include <hip/hip_runtime.h>
#include <math.h>

#define N_NODES 100000
#define N_EDGES 800000
#define HID 128
#define HEADS 4
#define HD 32

typedef __attribute__((ext_vector_type(8))) short short8;
typedef __attribute__((ext_vector_type(4))) float f32x4;

__device__ __forceinline__ unsigned int f2bf(float f) {
    unsigned int u = __float_as_uint(f);
    u += 0x7FFFu + ((u >> 16) & 1u);
    return (u >> 16) & 0xFFFFu;   // RNE round to bf16
}
__device__ __forceinline__ float bf_lo(unsigned int u) { return __uint_as_float(u << 16); }
__device__ __forceinline__ float bf_hi(unsigned int u) { return __uint_as_float(u & 0xFFFF0000u); }

// ---------------------------------------------------------------------------
// Prep: W[k][n] fp32 -> Wt bf16 [m][n][kc] chunks of 8 k (transposed, linear).
// ---------------------------------------------------------------------------
__global__ __launch_bounds__(256) void conv_w(
    const float* __restrict__ Wq, const float* __restrict__ Wk,
    const float* __restrict__ Wv, const float* __restrict__ Ws,
    uint4* __restrict__ wtbf)
{
    int idx = blockIdx.x * 256 + threadIdx.x;       // [4][128][16]
    if (idx >= 4 * 128 * 16) return;
    int m = idx >> 11, n = (idx >> 4) & 127, kc = idx & 15;
    const float* W = (m == 0) ? Wq : (m == 1) ? Wk : (m == 2) ? Wv : Ws;
    unsigned int h[8];
    #pragma unroll
    for (int j = 0; j < 8; ++j) h[j] = f2bf(W[(kc * 8 + j) * HID + n]);
    uint4 o;
    o.x = h[0] | (h[1] << 16);
    o.y = h[2] | (h[3] << 16);
    o.z = h[4] | (h[5] << 16);
    o.w = h[6] | (h[7] << 16);
    wtbf[idx] = o;
}

// ---------------------------------------------------------------------------
// MFMA projections, operand-swapped: D = W^T x X^T per 16x16 tile, so each
// lane's 4 acc regs are 4 CONSECUTIVE output columns of one x-row -> direct
// float4 (or packed bf16 uint2) global stores. No LDS epilogue.
// x rows load straight into registers. W staged to LDS in TWO PAIRS
// ({Wq,Wk} then {Wv,Ws}; 128 KB total does not fit in 64 KB at once).
// ---------------------------------------------------------------------------
__global__ __launch_bounds__(256) void proj_mfma(
    const float* __restrict__ x, const uint4* __restrict__ wtbf,
    const float* __restrict__ bq, const float* __restrict__ bk,
    const float* __restrict__ bv, const float* __restrict__ bs,
    float* __restrict__ Q, unsigned short* __restrict__ Kb,
    unsigned short* __restrict__ Vb, float* __restrict__ S)
{
    __shared__ uint4 wt[4096];          // 64 KB: TWO W matrices at a time

    const int rb   = blockIdx.x * 64;
    const int tid  = threadIdx.x;
    const int lane = tid & 63;
    const int w    = tid >> 6;
    const int r    = lane & 15;         // x-row within wave tile / W-n within nt tile
    const int kg   = lane >> 4;         // k-subgroup of 8

    // load this wave's 16 x-rows into bf16 fragments (before first barrier
    // so global latency overlaps the LDS staging)
    const int grow = rb + w * 16 + r;
    short8 afr[4];
    #pragma unroll
    for (int s = 0; s < 4; ++s) {
        float4 a = make_float4(0.f, 0.f, 0.f, 0.f);
        float4 b = make_float4(0.f, 0.f, 0.f, 0.f);
        if (grow < N_NODES) {
            const float4* p = (const float4*)(x + (size_t)grow * HID + (s * 4 + kg) * 8);
            a = p[0]; b = p[1];
        }
        uint4 o;
        o.x = f2bf(a.x) | (f2bf(a.y) << 16);
        o.y = f2bf(a.z) | (f2bf(a.w) << 16);
        o.z = f2bf(b.x) | (f2bf(b.y) << 16);
        o.w = f2bf(b.z) | (f2bf(b.w) << 16);
        afr[s] = *(short8*)&o;
    }

    #pragma unroll
    for (int pair = 0; pair < 2; ++pair) {
        if (pair == 1) __syncthreads();          // prior pair's reads done
        // stage this pair's two W tiles (swizzled chunk ^= n&7)
        #pragma unroll
        for (int it = 0; it < 16; ++it) {
            int cid = it * 256 + tid;            // [mh][n][kc] within pair
            int kc = cid & 15, n = (cid >> 4) & 127;
            wt[(cid & ~15) | (kc ^ (n & 7))] = wtbf[pair * 4096 + cid];
        }
        __syncthreads();

        #pragma unroll
        for (int mh = 0; mh < 2; ++mh) {
            const int m = pair * 2 + mh;
            const float* bias = (m == 0) ? bq : (m == 1) ? bk : (m == 2) ? bv : bs;
            const uint4* wtm = wt + mh * 2048;
            #pragma unroll
            for (int nt = 0; nt < 8; ++nt) {
                const int nrow = nt * 16 + r;
                const uint4* wrow = wtm + nrow * 16;
                f32x4 acc;
                acc[0] = 0.f; acc[1] = 0.f; acc[2] = 0.f; acc[3] = 0.f;
                #pragma unroll
                for (int s = 0; s < 4; ++s) {
                    short8 bfr = *(const short8*)&wrow[(s * 4 + kg) ^ (nrow & 7)];
                    acc = __builtin_amdgcn_mfma_f32_16x16x32_bf16(bfr, afr[s], acc, 0, 0, 0);
                }
                if (grow < N_NODES) {
                    const int col = nt * 16 + kg * 4;
                    float4 bi = *(const float4*)(bias + col);
                    float vx = acc[0] + bi.x, vy = acc[1] + bi.y;
                    float vz = acc[2] + bi.z, vw = acc[3] + bi.w;
                    if (m == 0) {
                        *(float4*)(Q + (size_t)grow * HID + col) = make_float4(vx, vy, vz, vw);
                    } else if (m == 3) {
                        *(float4*)(S + (size_t)grow * HID + col) = make_float4(vx, vy, vz, vw);
                    } else {
                        uint2 pk;
                        pk.x = f2bf(vx) | (f2bf(vy) << 16);
                        pk.y = f2bf(vz) | (f2bf(vw) << 16);
                        unsigned short* ob = (m == 1) ? Kb : Vb;
                        *(uint2*)(ob + (size_t)grow * HID + col) = pk;
                    }
                }
            }
        }
    }
}

// ---------------------------------------------------------------------------
// CSR build: histogram, hierarchical scan (49 blk -> 1 wave -> add), fill.
// ---------------------------------------------------------------------------
__global__ __launch_bounds__(256) void histo(const int* __restrict__ ei,
                                             int* __restrict__ deg)
{
    int e = blockIdx.x * 256 + threadIdx.x;
    if (e < N_EDGES) atomicAdd(&deg[ei[N_EDGES + e]], 1);
}

__global__ __launch_bounds__(256) void scan_local(const int* __restrict__ deg,
                                                  int* __restrict__ rowptr,
                                                  int* __restrict__ bsum)
{
    __shared__ int wsums[4];
    const int b = blockIdx.x, t = threadIdx.x, lane = t & 63, wid = t >> 6;
    const int base = b * 2048 + t * 8;
    int v[8], s = 0;
    #pragma unroll
    for (int j = 0; j < 8; ++j) {
        int i = base + j;
        v[j] = (i < N_NODES) ? deg[i] : 0;
        s += v[j];
    }
    const int tsum = s;
    int x = tsum;
    #pragma unroll
    for (int off = 1; off < 64; off <<= 1) {
        int t2 = __shfl_up(x, off);
        if (lane >= off) x += t2;
    }
    if (lane == 63) wsums[wid] = x;
    __syncthreads();
    int wpre = 0;
    #pragma unroll
    for (int ww = 0; ww < 4; ++ww) { if (ww < wid) wpre += wsums[ww]; }
    int run = wpre + x - tsum;
    #pragma unroll
    for (int j = 0; j < 8; ++j) {
        int i = base + j;
        if (i < N_NODES) rowptr[i] = run;
        run += v[j];
    }
    if (t == 0) bsum[b] = wsums[0] + wsums[1] + wsums[2] + wsums[3];
}

__global__ __launch_bounds__(64) void scan_bsum(int* __restrict__ bsum,
                                                int* __restrict__ rowptr,
                                                int nb)
{
    const int lane = threadIdx.x;
    int v = (lane < nb) ? bsum[lane] : 0;
    int x = v;
    #pragma unroll
    for (int off = 1; off < 64; off <<= 1) {
        int t2 = __shfl_up(x, off);
        if (lane >= off) x += t2;
    }
    if (lane < nb) bsum[lane] = x - v;     // exclusive
    if (lane == 63) rowptr[N_NODES] = x;   // grand total
}

__global__ __launch_bounds__(256) void add_off(int* __restrict__ rowptr,
                                               const int* __restrict__ bsum)
{
    int i = blockIdx.x * 256 + threadIdx.x;
    if (i < N_NODES) rowptr[i] += bsum[i >> 11];
}

__global__ __launch_bounds__(256) void csr_fill(const int* __restrict__ ei,
                                                const int* __restrict__ rowptr,
                                                int* __restrict__ fillctr,
                                                int* __restrict__ csr_src)
{
    int e = blockIdx.x * 256 + threadIdx.x;
    if (e >= N_EDGES) return;
    int src = ei[e], dst = ei[N_EDGES + e];
    int pos = rowptr[dst] + atomicAdd(&fillctr[dst], 1);
    csr_src[pos] = src;
}

// ---------------------------------------------------------------------------
// Fused per-node attention: one wave per node; two 32-lane halves process
// independent edge streams (even/odd CSR slots), 8 lanes per head-dot
// (3 shuffle levels), 2-edge unroll per half. Online softmax states merged
// across halves at the end. bf16 K/V gather; skip + LayerNorm fused.
// ---------------------------------------------------------------------------
__global__ __launch_bounds__(256) void node_attn(
    const int* __restrict__ rowptr, const int* __restrict__ csr_src,
    const float* __restrict__ Q, const unsigned short* __restrict__ Kb,
    const unsigned short* __restrict__ Vb, const float* __restrict__ S,
    const float* __restrict__ gamma, const float* __restrict__ beta,
    float* __restrict__ out)
{
    const int tid  = threadIdx.x;
    const int lane = tid & 63;
    const int wid  = tid >> 6;
    const int node = blockIdx.x * 4 + wid;
    if (node >= N_NODES) return;

    const int half = lane >> 5;
    const int l5   = lane & 31;
    const int j    = l5 * 4;               // dims j..j+3; head = l5>>3

    const int r0 = rowptr[node], r1 = rowptr[node + 1];

    float4 q4 = *(const float4*)(Q + (size_t)node * HID + j);

    float m = -INFINITY, den = 0.f;
    float ax = 0.f, ay = 0.f, az = 0.f, aw = 0.f;

    int p0 = r0 + half;
    int p1 = p0 + 2;
    bool h0 = p0 < r1, h1 = p1 < r1;

    uint2 k0 = {0,0}, v0 = {0,0}, k1 = {0,0}, v1 = {0,0};
    if (h0) { int s = csr_src[p0];
        k0 = *(const uint2*)(Kb + (size_t)s * HID + j);
        v0 = *(const uint2*)(Vb + (size_t)s * HID + j); }
    if (h1) { int s = csr_src[p1];
        k1 = *(const uint2*)(Kb + (size_t)s * HID + j);
        v1 = *(const uint2*)(Vb + (size_t)s * HID + j); }

    while (h0) {
        const int np0 = p0 + 4, np1 = p1 + 4;
        const bool nh0 = np0 < r1, nh1 = np1 < r1;
        uint2 k0n = {0,0}, v0n = {0,0}, k1n = {0,0}, v1n = {0,0};
        if (nh0) { int s = csr_src[np0];
            k0n = *(const uint2*)(Kb + (size_t)s * HID + j);
            v0n = *(const uint2*)(Vb + (size_t)s * HID + j); }
        if (nh1) { int s = csr_src[np1];
            k1n = *(const uint2*)(Kb + (size_t)s * HID + j);
            v1n = *(const uint2*)(Vb + (size_t)s * HID + j); }

        // two independent dot chains (each shfl serves both halves)
        float t0 = q4.x * bf_lo(k0.x) + q4.y * bf_hi(k0.x)
                 + q4.z * bf_lo(k0.y) + q4.w * bf_hi(k0.y);
        float t1 = q4.x * bf_lo(k1.x) + q4.y * bf_hi(k1.x)
                 + q4.z * bf_lo(k1.y) + q4.w * bf_hi(k1.y);
        t0 += __shfl_xor(t0, 1);  t1 += __shfl_xor(t1, 1);
        t0 += __shfl_xor(t0, 2);  t1 += __shfl_xor(t1, 2);
        t0 += __shfl_xor(t0, 4);  t1 += __shfl_xor(t1, 4);
        float a0 = t0 * 0.1767766952966369f;              // 1/sqrt(32)
        float a1 = h1 ? (t1 * 0.1767766952966369f) : -INFINITY;

        float mn = fmaxf(m, fmaxf(a0, a1));
        float sc = __expf(m - mn);                        // first iter: 0
        float e0 = __expf(a0 - mn);
        float e1 = h1 ? __expf(a1 - mn) : 0.f;
        den = den * sc + e0 + e1;
        ax = ax * sc + e0 * bf_lo(v0.x) + e1 * bf_lo(v1.x);
        ay = ay * sc + e0 * bf_hi(v0.x) + e1 * bf_hi(v1.x);
        az = az * sc + e0 * bf_lo(v0.y) + e1 * bf_lo(v1.y);
        aw = aw * sc + e0 * bf_hi(v0.y) + e1 * bf_hi(v1.y);
        m = mn;

        p0 = np0; p1 = np1; h0 = nh0; h1 = nh1;
        k0 = k0n; v0 = v0n; k1 = k1n; v1 = v1n;
    }

    // merge the two halves' online-softmax states (lanes l <-> l^32)
    float m_o   = __shfl_xor(m, 32);
    float den_o = __shfl_xor(den, 32);
    float ax_o = __shfl_xor(ax, 32);
    float ay_o = __shfl_xor(ay, 32);
    float az_o = __shfl_xor(az, 32);
    float aw_o = __shfl_xor(aw, 32);
    float mm  = fmaxf(m, m_o);
    float scs = (m   > -INFINITY) ? __expf(m   - mm) : 0.f;
    float sco = (m_o > -INFINITY) ? __expf(m_o - mm) : 0.f;
    float dent = den * scs + den_o * sco;
    float fx = ax * scs + ax_o * sco;
    float fy = ay * scs + ay_o * sco;
    float fz = az * scs + az_o * sco;
    float fw = aw * scs + aw_o * sco;

    float inv = 1.0f / (dent + 1e-16f);
    float4 s4 = *(const float4*)(S + (size_t)node * HID + j);
    float o0 = fx * inv + s4.x;
    float o1 = fy * inv + s4.y;
    float o2 = fz * inv + s4.z;
    float o3 = fw * inv + s4.w;

    // LayerNorm: reduce within each 32-lane half (both halves identical)
    float sum = o0 + o1 + o2 + o3;
    float sq  = o0 * o0 + o1 * o1 + o2 * o2 + o3 * o3;
    #pragma unroll
    for (int off = 1; off < 32; off <<= 1) {
        sum += __shfl_xor(sum, off);
        sq  += __shfl_xor(sq, off);
    }
    float mean = sum * (1.0f / 128.0f);
    float var  = sq * (1.0f / 128.0f) - mean * mean;
    float rstd = rsqrtf(var + 1e-5f);

    if (half == 0) {
        float4 g  = *(const float4*)(gamma + j);
        float4 bb = *(const float4*)(beta + j);
        float4 o;
        o.x = (o0 - mean) * rstd * g.x + bb.x;
        o.y = (o1 - mean) * rstd * g.y + bb.y;
        o.z = (o2 - mean) * rstd * g.z + bb.z;
        o.w = (o3 - mean) * rstd * g.w + bb.w;
        *(float4*)(out + (size_t)node * HID + j) = o;
    }
}

// ---------------------------------------------------------------------------
extern "C" void kernel_launch(void* const* d_in, const int* in_sizes, int n_in,
                              void* d_out, int out_size, void* d_ws, size_t ws_size,
                              hipStream_t stream) {
    const float* x  = (const float*)d_in[0];
    const int*   ei = (const int*)d_in[1];
    const float* Wq = (const float*)d_in[2];
    const float* bq = (const float*)d_in[3];
    const float* Wk = (const float*)d_in[4];
    const float* bk = (const float*)d_in[5];
    const float* Wv = (const float*)d_in[6];
    const float* bv = (const float*)d_in[7];
    const float* Ws = (const float*)d_in[8];
    const float* bs = (const float*)d_in[9];
    const float* gamma = (const float*)d_in[10];
    const float* beta  = (const float*)d_in[11];
    float* out = (float*)d_out;

    // workspace layout
    float* Q = (float*)d_ws;                               // [N,128] fp32
    float* S = Q + (size_t)N_NODES * HID;                  // [N,128] fp32
    unsigned short* Kb = (unsigned short*)(S + (size_t)N_NODES * HID);  // [N,128] bf16
    unsigned short* Vb = Kb + (size_t)N_NODES * HID;
    uint4* wtbf  = (uint4*)(Vb + (size_t)N_NODES * HID);   // [4*128*16]
    int* deg     = (int*)(wtbf + 4 * 128 * 16);
    int* rowptr  = deg + N_NODES;                          // N+1
    int* fillctr = rowptr + (N_NODES + 1);
    int* csr_src = fillctr + N_NODES;
    int* bsum    = csr_src + N_EDGES;                      // 64

    hipMemsetAsync(deg, 0, N_NODES * sizeof(int), stream);
    hipMemsetAsync(fillctr, 0, N_NODES * sizeof(int), stream);

    conv_w<<<32, 256, 0, stream>>>(Wq, Wk, Wv, Ws, wtbf);

    const int row_tiles = (N_NODES + 63) / 64;             // 1563
    proj_mfma<<<row_tiles, 256, 0, stream>>>(x, wtbf, bq, bk, bv, bs,
                                             Q, Kb, Vb, S);

    const int eblk = (N_EDGES + 255) / 256;                // 3125
    histo<<<eblk, 256, 0, stream>>>(ei, deg);
    const int nb = (N_NODES + 2047) / 2048;                // 49
    scan_local<<<nb, 256, 0, stream>>>(deg, rowptr, bsum);
    scan_bsum<<<1, 64, 0, stream>>>(bsum, rowptr, nb);
    add_off<<<(N_NODES + 255) / 256, 256, 0, stream>>>(rowptr, bsum);
    csr_fill<<<eblk, 256, 0, stream>>>(ei, rowptr, fillctr, csr_src);

    node_attn<<<(N_NODES + 3) / 4, 256, 0, stream>>>(rowptr, csr_src, Q, Kb, Vb, S,
                                                     gamma, beta, out);
}

// Round 8
// 242.535 us; speedup vs baseline: 13.5490x; 1.0286x over previous
//
#include <hip/hip_runtime.h>
#include <math.h>

#define N_NODES 100000
#define N_EDGES 800000
#define HID 128
#define HEADS 4
#define HD 32

typedef __attribute__((ext_vector_type(8))) short short8;
typedef __attribute__((ext_vector_type(4))) float f32x4;

__device__ __forceinline__ unsigned int f2bf(float f) {
    unsigned int u = __float_as_uint(f);
    u += 0x7FFFu + ((u >> 16) & 1u);
    return (u >> 16) & 0xFFFFu;   // RNE round to bf16
}
__device__ __forceinline__ float bf_lo(unsigned int u) { return __uint_as_float(u << 16); }
__device__ __forceinline__ float bf_hi(unsigned int u) { return __uint_as_float(u & 0xFFFF0000u); }

// ---------------------------------------------------------------------------
// Prep: W[k][n] fp32 -> Wt bf16 [m][n][kc] chunks of 8 k (transposed, linear).
// ---------------------------------------------------------------------------
__global__ __launch_bounds__(256) void conv_w(
    const float* __restrict__ Wq, const float* __restrict__ Wk,
    const float* __restrict__ Wv, const float* __restrict__ Ws,
    uint4* __restrict__ wtbf)
{
    int idx = blockIdx.x * 256 + threadIdx.x;       // [4][128][16]
    if (idx >= 4 * 128 * 16) return;
    int m = idx >> 11, n = (idx >> 4) & 127, kc = idx & 15;
    const float* W = (m == 0) ? Wq : (m == 1) ? Wk : (m == 2) ? Wv : Ws;
    unsigned int h[8];
    #pragma unroll
    for (int j = 0; j < 8; ++j) h[j] = f2bf(W[(kc * 8 + j) * HID + n]);
    uint4 o;
    o.x = h[0] | (h[1] << 16);
    o.y = h[2] | (h[3] << 16);
    o.z = h[4] | (h[5] << 16);
    o.w = h[6] | (h[7] << 16);
    wtbf[idx] = o;
}

// ---------------------------------------------------------------------------
// MFMA projections, operand-swapped: each lane's 4 acc regs are 4 CONSECUTIVE
// output columns of one x-row -> direct coalesced stores, no LDS epilogue.
// 512 threads / 128 rows per block (halves W-staging overhead, 16 waves/CU).
// W staged in TWO PAIRS ({Wq,Wk}, {Wv,Ws}); Q,K,V out bf16; S out fp32.
// ---------------------------------------------------------------------------
__global__ __launch_bounds__(512) void proj_mfma(
    const float* __restrict__ x, const uint4* __restrict__ wtbf,
    const float* __restrict__ bq, const float* __restrict__ bk,
    const float* __restrict__ bv, const float* __restrict__ bs,
    unsigned short* __restrict__ Qb, unsigned short* __restrict__ Kb,
    unsigned short* __restrict__ Vb, float* __restrict__ S)
{
    __shared__ uint4 wt[4096];          // 64 KB: TWO W matrices at a time

    const int rb   = blockIdx.x * 128;
    const int tid  = threadIdx.x;
    const int lane = tid & 63;
    const int w    = tid >> 6;          // 0..7
    const int r    = lane & 15;
    const int kg   = lane >> 4;

    // load this wave's 16 x-rows into bf16 fragments (before first barrier)
    const int grow = rb + w * 16 + r;
    short8 afr[4];
    #pragma unroll
    for (int s = 0; s < 4; ++s) {
        float4 a = make_float4(0.f, 0.f, 0.f, 0.f);
        float4 b = make_float4(0.f, 0.f, 0.f, 0.f);
        if (grow < N_NODES) {
            const float4* p = (const float4*)(x + (size_t)grow * HID + (s * 4 + kg) * 8);
            a = p[0]; b = p[1];
        }
        uint4 o;
        o.x = f2bf(a.x) | (f2bf(a.y) << 16);
        o.y = f2bf(a.z) | (f2bf(a.w) << 16);
        o.z = f2bf(b.x) | (f2bf(b.y) << 16);
        o.w = f2bf(b.z) | (f2bf(b.w) << 16);
        afr[s] = *(short8*)&o;
    }

    #pragma unroll
    for (int pair = 0; pair < 2; ++pair) {
        if (pair == 1) __syncthreads();          // prior pair's reads done
        #pragma unroll
        for (int it = 0; it < 16; ++it) {
            int cid = it * 512 + tid;            // [mh][n][kc] within pair
            int kc = cid & 15, n = (cid >> 4) & 127;
            wt[(cid & ~15) | (kc ^ (n & 7))] = wtbf[pair * 4096 + cid];
        }
        __syncthreads();

        #pragma unroll
        for (int mh = 0; mh < 2; ++mh) {
            const int m = pair * 2 + mh;
            const float* bias = (m == 0) ? bq : (m == 1) ? bk : (m == 2) ? bv : bs;
            const uint4* wtm = wt + mh * 2048;
            #pragma unroll
            for (int nt = 0; nt < 8; ++nt) {
                const int nrow = nt * 16 + r;
                const uint4* wrow = wtm + nrow * 16;
                f32x4 acc;
                acc[0] = 0.f; acc[1] = 0.f; acc[2] = 0.f; acc[3] = 0.f;
                #pragma unroll
                for (int s = 0; s < 4; ++s) {
                    short8 bfr = *(const short8*)&wrow[(s * 4 + kg) ^ (nrow & 7)];
                    acc = __builtin_amdgcn_mfma_f32_16x16x32_bf16(bfr, afr[s], acc, 0, 0, 0);
                }
                if (grow < N_NODES) {
                    const int col = nt * 16 + kg * 4;
                    float4 bi = *(const float4*)(bias + col);
                    float vx = acc[0] + bi.x, vy = acc[1] + bi.y;
                    float vz = acc[2] + bi.z, vw = acc[3] + bi.w;
                    if (m == 3) {
                        *(float4*)(S + (size_t)grow * HID + col) = make_float4(vx, vy, vz, vw);
                    } else {
                        uint2 pk;
                        pk.x = f2bf(vx) | (f2bf(vy) << 16);
                        pk.y = f2bf(vz) | (f2bf(vw) << 16);
                        unsigned short* ob = (m == 0) ? Qb : (m == 1) ? Kb : Vb;
                        *(uint2*)(ob + (size_t)grow * HID + col) = pk;
                    }
                }
            }
        }
    }
}

// ---------------------------------------------------------------------------
// CSR build: histogram, hierarchical scan (49 blk -> 1 wave -> add), fill.
// ---------------------------------------------------------------------------
__global__ __launch_bounds__(256) void histo(const int* __restrict__ ei,
                                             int* __restrict__ deg)
{
    int e = blockIdx.x * 256 + threadIdx.x;
    if (e < N_EDGES) atomicAdd(&deg[ei[N_EDGES + e]], 1);
}

__global__ __launch_bounds__(256) void scan_local(const int* __restrict__ deg,
                                                  int* __restrict__ rowptr,
                                                  int* __restrict__ bsum)
{
    __shared__ int wsums[4];
    const int b = blockIdx.x, t = threadIdx.x, lane = t & 63, wid = t >> 6;
    const int base = b * 2048 + t * 8;
    int v[8], s = 0;
    #pragma unroll
    for (int j = 0; j < 8; ++j) {
        int i = base + j;
        v[j] = (i < N_NODES) ? deg[i] : 0;
        s += v[j];
    }
    const int tsum = s;
    int x = tsum;
    #pragma unroll
    for (int off = 1; off < 64; off <<= 1) {
        int t2 = __shfl_up(x, off);
        if (lane >= off) x += t2;
    }
    if (lane == 63) wsums[wid] = x;
    __syncthreads();
    int wpre = 0;
    #pragma unroll
    for (int ww = 0; ww < 4; ++ww) { if (ww < wid) wpre += wsums[ww]; }
    int run = wpre + x - tsum;
    #pragma unroll
    for (int j = 0; j < 8; ++j) {
        int i = base + j;
        if (i < N_NODES) rowptr[i] = run;
        run += v[j];
    }
    if (t == 0) bsum[b] = wsums[0] + wsums[1] + wsums[2] + wsums[3];
}

__global__ __launch_bounds__(64) void scan_bsum(int* __restrict__ bsum,
                                                int* __restrict__ rowptr,
                                                int nb)
{
    const int lane = threadIdx.x;
    int v = (lane < nb) ? bsum[lane] : 0;
    int x = v;
    #pragma unroll
    for (int off = 1; off < 64; off <<= 1) {
        int t2 = __shfl_up(x, off);
        if (lane >= off) x += t2;
    }
    if (lane < nb) bsum[lane] = x - v;     // exclusive
    if (lane == 63) rowptr[N_NODES] = x;   // grand total
}

__global__ __launch_bounds__(256) void add_off(int* __restrict__ rowptr,
                                               const int* __restrict__ bsum)
{
    int i = blockIdx.x * 256 + threadIdx.x;
    if (i < N_NODES) rowptr[i] += bsum[i >> 11];
}

__global__ __launch_bounds__(256) void csr_fill(const int* __restrict__ ei,
                                                const int* __restrict__ rowptr,
                                                int* __restrict__ fillctr,
                                                int* __restrict__ csr_src)
{
    int e = blockIdx.x * 256 + threadIdx.x;
    if (e >= N_EDGES) return;
    int src = ei[e], dst = ei[N_EDGES + e];
    int pos = rowptr[dst] + atomicAdd(&fillctr[dst], 1);
    csr_src[pos] = src;
}

// ---------------------------------------------------------------------------
// Fused per-node attention, DIRECT-EXP softmax (logits bounded => no max
// tracking; mathematically identical, removes the serial m/rescale chain).
// One wave per node; two 32-lane halves on even/odd CSR slots, 8 lanes per
// head-dot, 2-edge unroll per half. bf16 Q/K/V; skip + LayerNorm fused.
// ---------------------------------------------------------------------------
__global__ __launch_bounds__(256) void node_attn(
    const int* __restrict__ rowptr, const int* __restrict__ csr_src,
    const unsigned short* __restrict__ Qb, const unsigned short* __restrict__ Kb,
    const unsigned short* __restrict__ Vb, const float* __restrict__ S,
    const float* __restrict__ gamma, const float* __restrict__ beta,
    float* __restrict__ out)
{
    const int tid  = threadIdx.x;
    const int lane = tid & 63;
    const int wid  = tid >> 6;
    const int node = blockIdx.x * 4 + wid;
    if (node >= N_NODES) return;

    const int half = lane >> 5;
    const int l5   = lane & 31;
    const int j    = l5 * 4;               // dims j..j+3; head = l5>>3

    const int r0 = rowptr[node], r1 = rowptr[node + 1];

    uint2 qp = *(const uint2*)(Qb + (size_t)node * HID + j);
    const float qx = bf_lo(qp.x), qy = bf_hi(qp.x);
    const float qz = bf_lo(qp.y), qw = bf_hi(qp.y);

    float den = 0.f, ax = 0.f, ay = 0.f, az = 0.f, aw = 0.f;

    int p0 = r0 + half;
    int p1 = p0 + 2;
    bool h0 = p0 < r1, h1 = p1 < r1;

    uint2 k0 = {0,0}, v0 = {0,0}, k1 = {0,0}, v1 = {0,0};
    if (h0) { int s = csr_src[p0];
        k0 = *(const uint2*)(Kb + (size_t)s * HID + j);
        v0 = *(const uint2*)(Vb + (size_t)s * HID + j); }
    if (h1) { int s = csr_src[p1];
        k1 = *(const uint2*)(Kb + (size_t)s * HID + j);
        v1 = *(const uint2*)(Vb + (size_t)s * HID + j); }

    while (h0) {
        const int np0 = p0 + 4, np1 = p1 + 4;
        const bool nh0 = np0 < r1, nh1 = np1 < r1;
        uint2 k0n = {0,0}, v0n = {0,0}, k1n = {0,0}, v1n = {0,0};
        if (nh0) { int s = csr_src[np0];
            k0n = *(const uint2*)(Kb + (size_t)s * HID + j);
            v0n = *(const uint2*)(Vb + (size_t)s * HID + j); }
        if (nh1) { int s = csr_src[np1];
            k1n = *(const uint2*)(Kb + (size_t)s * HID + j);
            v1n = *(const uint2*)(Vb + (size_t)s * HID + j); }

        // two independent dot chains (each shfl serves both halves)
        float t0 = qx * bf_lo(k0.x) + qy * bf_hi(k0.x)
                 + qz * bf_lo(k0.y) + qw * bf_hi(k0.y);
        float t1 = qx * bf_lo(k1.x) + qy * bf_hi(k1.x)
                 + qz * bf_lo(k1.y) + qw * bf_hi(k1.y);
        t0 += __shfl_xor(t0, 1);  t1 += __shfl_xor(t1, 1);
        t0 += __shfl_xor(t0, 2);  t1 += __shfl_xor(t1, 2);
        t0 += __shfl_xor(t0, 4);  t1 += __shfl_xor(t1, 4);

        float e0 = __expf(t0 * 0.1767766952966369f);      // 1/sqrt(32)
        float e1 = h1 ? __expf(t1 * 0.1767766952966369f) : 0.f;
        den += e0 + e1;
        ax += e0 * bf_lo(v0.x) + e1 * bf_lo(v1.x);
        ay += e0 * bf_hi(v0.x) + e1 * bf_hi(v1.x);
        az += e0 * bf_lo(v0.y) + e1 * bf_lo(v1.y);
        aw += e0 * bf_hi(v0.y) + e1 * bf_hi(v1.y);

        p0 = np0; p1 = np1; h0 = nh0; h1 = nh1;
        k0 = k0n; v0 = v0n; k1 = k1n; v1 = v1n;
    }

    // merge the two halves (lanes l <-> l^32): plain sums
    den += __shfl_xor(den, 32);
    ax  += __shfl_xor(ax, 32);
    ay  += __shfl_xor(ay, 32);
    az  += __shfl_xor(az, 32);
    aw  += __shfl_xor(aw, 32);

    float inv = 1.0f / (den + 1e-16f);
    float4 s4 = *(const float4*)(S + (size_t)node * HID + j);
    float o0 = ax * inv + s4.x;
    float o1 = ay * inv + s4.y;
    float o2 = az * inv + s4.z;
    float o3 = aw * inv + s4.w;

    // LayerNorm: reduce within each 32-lane half (both halves identical)
    float sum = o0 + o1 + o2 + o3;
    float sq  = o0 * o0 + o1 * o1 + o2 * o2 + o3 * o3;
    #pragma unroll
    for (int off = 1; off < 32; off <<= 1) {
        sum += __shfl_xor(sum, off);
        sq  += __shfl_xor(sq, off);
    }
    float mean = sum * (1.0f / 128.0f);
    float var  = sq * (1.0f / 128.0f) - mean * mean;
    float rstd = rsqrtf(var + 1e-5f);

    if (half == 0) {
        float4 g  = *(const float4*)(gamma + j);
        float4 bb = *(const float4*)(beta + j);
        float4 o;
        o.x = (o0 - mean) * rstd * g.x + bb.x;
        o.y = (o1 - mean) * rstd * g.y + bb.y;
        o.z = (o2 - mean) * rstd * g.z + bb.z;
        o.w = (o3 - mean) * rstd * g.w + bb.w;
        *(float4*)(out + (size_t)node * HID + j) = o;
    }
}

// ---------------------------------------------------------------------------
extern "C" void kernel_launch(void* const* d_in, const int* in_sizes, int n_in,
                              void* d_out, int out_size, void* d_ws, size_t ws_size,
                              hipStream_t stream) {
    const float* x  = (const float*)d_in[0];
    const int*   ei = (const int*)d_in[1];
    const float* Wq = (const float*)d_in[2];
    const float* bq = (const float*)d_in[3];
    const float* Wk = (const float*)d_in[4];
    const float* bk = (const float*)d_in[5];
    const float* Wv = (const float*)d_in[6];
    const float* bv = (const float*)d_in[7];
    const float* Ws = (const float*)d_in[8];
    const float* bs = (const float*)d_in[9];
    const float* gamma = (const float*)d_in[10];
    const float* beta  = (const float*)d_in[11];
    float* out = (float*)d_out;

    // workspace layout
    float* S = (float*)d_ws;                               // [N,128] fp32
    unsigned short* Qb = (unsigned short*)(S + (size_t)N_NODES * HID);  // bf16
    unsigned short* Kb = Qb + (size_t)N_NODES * HID;
    unsigned short* Vb = Kb + (size_t)N_NODES * HID;
    uint4* wtbf  = (uint4*)(Vb + (size_t)N_NODES * HID);   // [4*128*16]
    int* deg     = (int*)(wtbf + 4 * 128 * 16);
    int* rowptr  = deg + N_NODES;                          // N+1
    int* fillctr = rowptr + (N_NODES + 1);
    int* csr_src = fillctr + N_NODES;
    int* bsum    = csr_src + N_EDGES;                      // 64

    hipMemsetAsync(deg, 0, N_NODES * sizeof(int), stream);
    hipMemsetAsync(fillctr, 0, N_NODES * sizeof(int), stream);

    conv_w<<<32, 256, 0, stream>>>(Wq, Wk, Wv, Ws, wtbf);

    const int row_tiles = (N_NODES + 127) / 128;           // 782
    proj_mfma<<<row_tiles, 512, 0, stream>>>(x, wtbf, bq, bk, bv, bs,
                                             Qb, Kb, Vb, S);

    const int eblk = (N_EDGES + 255) / 256;                // 3125
    histo<<<eblk, 256, 0, stream>>>(ei, deg);
    const int nb = (N_NODES + 2047) / 2048;                // 49
    scan_local<<<nb, 256, 0, stream>>>(deg, rowptr, bsum);
    scan_bsum<<<1, 64, 0, stream>>>(bsum, rowptr, nb);
    add_off<<<(N_NODES + 255) / 256, 256, 0, stream>>>(rowptr, bsum);
    csr_fill<<<eblk, 256, 0, stream>>>(ei, rowptr, fillctr, csr_src);

    node_attn<<<(N_NODES + 3) / 4, 256, 0, stream>>>(rowptr, csr_src, Qb, Kb, Vb, S,
                                                     gamma, beta, out);
}

// Round 9
// 225.353 us; speedup vs baseline: 14.5821x; 1.0762x over previous
//
#include <hip/hip_runtime.h>
#include <math.h>

#define N_NODES 100000
#define N_EDGES 800000
#define HID 128
#define HEADS 4
#define HD 32

#define KSCALE 0.17677669529663687f   // 1/sqrt(32), folded into K projection

typedef __attribute__((ext_vector_type(8))) short short8;
typedef __attribute__((ext_vector_type(4))) float f32x4;

__device__ __forceinline__ unsigned int f2bf(float f) {
    unsigned int u = __float_as_uint(f);
    u += 0x7FFFu + ((u >> 16) & 1u);
    return (u >> 16) & 0xFFFFu;   // RNE round to bf16
}
__device__ __forceinline__ float bf_lo(unsigned int u) { return __uint_as_float(u << 16); }
__device__ __forceinline__ float bf_hi(unsigned int u) { return __uint_as_float(u & 0xFFFF0000u); }

// ---------------------------------------------------------------------------
// prep: blocks 0..31 convert W fp32 -> bf16 transposed chunks; remaining
// blocks histogram edge destinations. (fused to cut a launch)
// ---------------------------------------------------------------------------
__global__ __launch_bounds__(256) void prep(
    const float* __restrict__ Wq, const float* __restrict__ Wk,
    const float* __restrict__ Wv, const float* __restrict__ Ws,
    uint4* __restrict__ wtbf, const int* __restrict__ ei,
    int* __restrict__ deg)
{
    const int b = blockIdx.x;
    if (b < 32) {
        int idx = b * 256 + threadIdx.x;        // [4][128][16]
        int m = idx >> 11, n = (idx >> 4) & 127, kc = idx & 15;
        const float* W = (m == 0) ? Wq : (m == 1) ? Wk : (m == 2) ? Wv : Ws;
        unsigned int h[8];
        #pragma unroll
        for (int j = 0; j < 8; ++j) h[j] = f2bf(W[(kc * 8 + j) * HID + n]);
        uint4 o;
        o.x = h[0] | (h[1] << 16);
        o.y = h[2] | (h[3] << 16);
        o.z = h[4] | (h[5] << 16);
        o.w = h[6] | (h[7] << 16);
        wtbf[idx] = o;
    } else {
        int e = (b - 32) * 256 + threadIdx.x;
        if (e < N_EDGES) atomicAdd(&deg[ei[N_EDGES + e]], 1);
    }
}

// ---------------------------------------------------------------------------
// MFMA projections, operand-swapped. Outputs ALL bf16:
//   Qb[node][128], KVb[node][256] (K scaled by 1/sqrt(32) | V), Sb[node][128].
// ---------------------------------------------------------------------------
__global__ __launch_bounds__(512) void proj_mfma(
    const float* __restrict__ x, const uint4* __restrict__ wtbf,
    const float* __restrict__ bq, const float* __restrict__ bk,
    const float* __restrict__ bv, const float* __restrict__ bs,
    unsigned short* __restrict__ Qb, unsigned short* __restrict__ KVb,
    unsigned short* __restrict__ Sb)
{
    __shared__ uint4 wt[4096];          // 64 KB: TWO W matrices at a time

    const int rb   = blockIdx.x * 128;
    const int tid  = threadIdx.x;
    const int lane = tid & 63;
    const int w    = tid >> 6;          // 0..7
    const int r    = lane & 15;
    const int kg   = lane >> 4;

    // load this wave's 16 x-rows into bf16 fragments (before first barrier)
    const int grow = rb + w * 16 + r;
    short8 afr[4];
    #pragma unroll
    for (int s = 0; s < 4; ++s) {
        float4 a = make_float4(0.f, 0.f, 0.f, 0.f);
        float4 b = make_float4(0.f, 0.f, 0.f, 0.f);
        if (grow < N_NODES) {
            const float4* p = (const float4*)(x + (size_t)grow * HID + (s * 4 + kg) * 8);
            a = p[0]; b = p[1];
        }
        uint4 o;
        o.x = f2bf(a.x) | (f2bf(a.y) << 16);
        o.y = f2bf(a.z) | (f2bf(a.w) << 16);
        o.z = f2bf(b.x) | (f2bf(b.y) << 16);
        o.w = f2bf(b.z) | (f2bf(b.w) << 16);
        afr[s] = *(short8*)&o;
    }

    #pragma unroll
    for (int pair = 0; pair < 2; ++pair) {
        if (pair == 1) __syncthreads();          // prior pair's reads done
        #pragma unroll
        for (int it = 0; it < 16; ++it) {
            int cid = it * 512 + tid;            // [mh][n][kc] within pair
            int kc = cid & 15, n = (cid >> 4) & 127;
            wt[(cid & ~15) | (kc ^ (n & 7))] = wtbf[pair * 4096 + cid];
        }
        __syncthreads();

        #pragma unroll
        for (int mh = 0; mh < 2; ++mh) {
            const int m = pair * 2 + mh;
            const float* bias = (m == 0) ? bq : (m == 1) ? bk : (m == 2) ? bv : bs;
            const uint4* wtm = wt + mh * 2048;
            #pragma unroll
            for (int nt = 0; nt < 8; ++nt) {
                const int nrow = nt * 16 + r;
                const uint4* wrow = wtm + nrow * 16;
                f32x4 acc;
                acc[0] = 0.f; acc[1] = 0.f; acc[2] = 0.f; acc[3] = 0.f;
                #pragma unroll
                for (int s = 0; s < 4; ++s) {
                    short8 bfr = *(const short8*)&wrow[(s * 4 + kg) ^ (nrow & 7)];
                    acc = __builtin_amdgcn_mfma_f32_16x16x32_bf16(bfr, afr[s], acc, 0, 0, 0);
                }
                if (grow < N_NODES) {
                    const int col = nt * 16 + kg * 4;
                    float4 bi = *(const float4*)(bias + col);
                    float vx = acc[0] + bi.x, vy = acc[1] + bi.y;
                    float vz = acc[2] + bi.z, vw = acc[3] + bi.w;
                    if (m == 1) { vx *= KSCALE; vy *= KSCALE; vz *= KSCALE; vw *= KSCALE; }
                    uint2 pk;
                    pk.x = f2bf(vx) | (f2bf(vy) << 16);
                    pk.y = f2bf(vz) | (f2bf(vw) << 16);
                    unsigned short* dst =
                        (m == 0) ? (Qb + (size_t)grow * HID + col) :
                        (m == 1) ? (KVb + (size_t)grow * 256 + col) :
                        (m == 2) ? (KVb + (size_t)grow * 256 + 128 + col) :
                                   (Sb + (size_t)grow * HID + col);
                    *(uint2*)dst = pk;
                }
            }
        }
    }
}

// ---------------------------------------------------------------------------
// CSR build: hierarchical scan (49 blk local -> fused offset add), fill.
// ---------------------------------------------------------------------------
__global__ __launch_bounds__(256) void scan_local(const int* __restrict__ deg,
                                                  int* __restrict__ rowptr,
                                                  int* __restrict__ bsum)
{
    __shared__ int wsums[4];
    const int b = blockIdx.x, t = threadIdx.x, lane = t & 63, wid = t >> 6;
    const int base = b * 2048 + t * 8;
    int v[8], s = 0;
    #pragma unroll
    for (int j = 0; j < 8; ++j) {
        int i = base + j;
        v[j] = (i < N_NODES) ? deg[i] : 0;
        s += v[j];
    }
    const int tsum = s;
    int x = tsum;
    #pragma unroll
    for (int off = 1; off < 64; off <<= 1) {
        int t2 = __shfl_up(x, off);
        if (lane >= off) x += t2;
    }
    if (lane == 63) wsums[wid] = x;
    __syncthreads();
    int wpre = 0;
    #pragma unroll
    for (int ww = 0; ww < 4; ++ww) { if (ww < wid) wpre += wsums[ww]; }
    int run = wpre + x - tsum;
    #pragma unroll
    for (int j = 0; j < 8; ++j) {
        int i = base + j;
        if (i < N_NODES) rowptr[i] = run;
        run += v[j];
    }
    if (t == 0) bsum[b] = wsums[0] + wsums[1] + wsums[2] + wsums[3];
}

// add block-offset (each block redundantly wave-reduces bsum prefix; cheap)
__global__ __launch_bounds__(256) void add_off(int* __restrict__ rowptr,
                                               const int* __restrict__ bsum)
{
    __shared__ int offs;
    const int t = threadIdx.x;
    const int tgt = blockIdx.x >> 3;       // 2048-node groups / 256-node blocks
    if (t < 64) {
        int v = (t < tgt) ? bsum[t] : 0;
        #pragma unroll
        for (int off = 1; off < 64; off <<= 1) v += __shfl_xor(v, off);
        if (t == 0) offs = v;
    }
    __syncthreads();
    int i = blockIdx.x * 256 + t;
    if (i < N_NODES) rowptr[i] += offs;
    if (blockIdx.x == 0 && t == 0) rowptr[N_NODES] = N_EDGES;
}

// fill: reuse deg (still intact) as countdown -> no fillctr array/memset
__global__ __launch_bounds__(256) void csr_fill(const int* __restrict__ ei,
                                                const int* __restrict__ rowptr,
                                                int* __restrict__ deg,
                                                int* __restrict__ csr_src)
{
    int e = blockIdx.x * 256 + threadIdx.x;
    if (e >= N_EDGES) return;
    int src = ei[e], dst = ei[N_EDGES + e];
    int old = atomicSub(&deg[dst], 1);
    csr_src[rowptr[dst] + old - 1] = src;
}

// ---------------------------------------------------------------------------
// Fused per-node attention: one wave per node; FOUR 16-lane edge slots
// (8 dims/lane, uint4 loads, 2 shfl levels per dot, shared exp). Direct-exp
// softmax (logits bounded; K pre-scaled by 1/sqrt(32)). KV interleaved rows;
// slot merge at end; skip + LayerNorm fused. All inputs bf16.
// ---------------------------------------------------------------------------
__global__ __launch_bounds__(256) void node_attn(
    const int* __restrict__ rowptr, const int* __restrict__ csr_src,
    const unsigned short* __restrict__ Qb, const unsigned short* __restrict__ KVb,
    const unsigned short* __restrict__ Sb,
    const float* __restrict__ gamma, const float* __restrict__ beta,
    float* __restrict__ out)
{
    const int tid  = threadIdx.x;
    const int lane = tid & 63;
    const int node = blockIdx.x * 4 + (tid >> 6);
    if (node >= N_NODES) return;

    const int l16 = lane & 15;
    const int es  = lane >> 4;            // edge slot 0..3
    const int j8  = l16 * 8;              // dims j8..j8+7; head = l16>>2

    const int r0 = rowptr[node], r1 = rowptr[node + 1];

    uint4 qp = *(const uint4*)(Qb + (size_t)node * HID + j8);
    const float q0 = bf_lo(qp.x), q1 = bf_hi(qp.x);
    const float q2 = bf_lo(qp.y), q3 = bf_hi(qp.y);
    const float q4 = bf_lo(qp.z), q5 = bf_hi(qp.z);
    const float q6 = bf_lo(qp.w), q7 = bf_hi(qp.w);

    float den = 0.f;
    float a0 = 0.f, a1 = 0.f, a2 = 0.f, a3 = 0.f;
    float a4 = 0.f, a5 = 0.f, a6 = 0.f, a7 = 0.f;

    int p = r0 + es;
    uint4 kc = {0,0,0,0}, vc = {0,0,0,0};
    if (p < r1) {
        const unsigned short* base = KVb + (size_t)csr_src[p] * 256;
        kc = *(const uint4*)(base + j8);
        vc = *(const uint4*)(base + 128 + j8);
    }

    for (int it = r0; it < r1; it += 4) {
        // prefetch next slot edge
        uint4 kn = {0,0,0,0}, vn = {0,0,0,0};
        const int pn = p + 4;
        if (pn < r1) {
            const unsigned short* base = KVb + (size_t)csr_src[pn] * 256;
            kn = *(const uint4*)(base + j8);
            vn = *(const uint4*)(base + 128 + j8);
        }

        float t = q0 * bf_lo(kc.x) + q1 * bf_hi(kc.x)
                + q2 * bf_lo(kc.y) + q3 * bf_hi(kc.y)
                + q4 * bf_lo(kc.z) + q5 * bf_hi(kc.z)
                + q6 * bf_lo(kc.w) + q7 * bf_hi(kc.w);
        t += __shfl_xor(t, 1);
        t += __shfl_xor(t, 2);              // 4-lane head group complete

        float e = (p < r1) ? __expf(t) : 0.f;
        den += e;
        a0 += e * bf_lo(vc.x); a1 += e * bf_hi(vc.x);
        a2 += e * bf_lo(vc.y); a3 += e * bf_hi(vc.y);
        a4 += e * bf_lo(vc.z); a5 += e * bf_hi(vc.z);
        a6 += e * bf_lo(vc.w); a7 += e * bf_hi(vc.w);

        p = pn; kc = kn; vc = vn;
    }

    // merge the 4 edge slots (lanes ^16, ^32)
    #pragma unroll
    for (int msk = 16; msk <= 32; msk <<= 1) {
        den += __shfl_xor(den, msk);
        a0 += __shfl_xor(a0, msk); a1 += __shfl_xor(a1, msk);
        a2 += __shfl_xor(a2, msk); a3 += __shfl_xor(a3, msk);
        a4 += __shfl_xor(a4, msk); a5 += __shfl_xor(a5, msk);
        a6 += __shfl_xor(a6, msk); a7 += __shfl_xor(a7, msk);
    }

    float inv = 1.0f / (den + 1e-16f);
    uint4 sp = *(const uint4*)(Sb + (size_t)node * HID + j8);
    float o0 = a0 * inv + bf_lo(sp.x), o1 = a1 * inv + bf_hi(sp.x);
    float o2 = a2 * inv + bf_lo(sp.y), o3 = a3 * inv + bf_hi(sp.y);
    float o4 = a4 * inv + bf_lo(sp.z), o5 = a5 * inv + bf_hi(sp.z);
    float o6 = a6 * inv + bf_lo(sp.w), o7 = a7 * inv + bf_hi(sp.w);

    // LayerNorm reduce over 16 lanes (all slots hold identical data now)
    float sum = (o0 + o1) + (o2 + o3) + (o4 + o5) + (o6 + o7);
    float sq  = o0*o0 + o1*o1 + o2*o2 + o3*o3 + o4*o4 + o5*o5 + o6*o6 + o7*o7;
    #pragma unroll
    for (int off = 1; off < 16; off <<= 1) {
        sum += __shfl_xor(sum, off);
        sq  += __shfl_xor(sq, off);
    }
    float mean = sum * (1.0f / 128.0f);
    float var  = sq * (1.0f / 128.0f) - mean * mean;
    float rstd = rsqrtf(var + 1e-5f);

    if (es == 0) {
        float4 g0 = *(const float4*)(gamma + j8);
        float4 g1 = *(const float4*)(gamma + j8 + 4);
        float4 b0 = *(const float4*)(beta + j8);
        float4 b1 = *(const float4*)(beta + j8 + 4);
        float4 w0, w1;
        w0.x = (o0 - mean) * rstd * g0.x + b0.x;
        w0.y = (o1 - mean) * rstd * g0.y + b0.y;
        w0.z = (o2 - mean) * rstd * g0.z + b0.z;
        w0.w = (o3 - mean) * rstd * g0.w + b0.w;
        w1.x = (o4 - mean) * rstd * g1.x + b1.x;
        w1.y = (o5 - mean) * rstd * g1.y + b1.y;
        w1.z = (o6 - mean) * rstd * g1.z + b1.z;
        w1.w = (o7 - mean) * rstd * g1.w + b1.w;
        float* op = out + (size_t)node * HID + j8;
        *(float4*)op = w0;
        *(float4*)(op + 4) = w1;
    }
}

// ---------------------------------------------------------------------------
extern "C" void kernel_launch(void* const* d_in, const int* in_sizes, int n_in,
                              void* d_out, int out_size, void* d_ws, size_t ws_size,
                              hipStream_t stream) {
    const float* x  = (const float*)d_in[0];
    const int*   ei = (const int*)d_in[1];
    const float* Wq = (const float*)d_in[2];
    const float* bq = (const float*)d_in[3];
    const float* Wk = (const float*)d_in[4];
    const float* bk = (const float*)d_in[5];
    const float* Wv = (const float*)d_in[6];
    const float* bv = (const float*)d_in[7];
    const float* Ws = (const float*)d_in[8];
    const float* bs = (const float*)d_in[9];
    const float* gamma = (const float*)d_in[10];
    const float* beta  = (const float*)d_in[11];
    float* out = (float*)d_out;

    // workspace layout (all bf16 feature buffers)
    unsigned short* Qb  = (unsigned short*)d_ws;               // [N,128]
    unsigned short* KVb = Qb + (size_t)N_NODES * HID;          // [N,256]
    unsigned short* Sb  = KVb + (size_t)N_NODES * 256;         // [N,128]
    uint4* wtbf  = (uint4*)(Sb + (size_t)N_NODES * HID);       // [4*128*16]
    int* deg     = (int*)(wtbf + 4 * 128 * 16);
    int* rowptr  = deg + N_NODES;                              // N+1
    int* csr_src = rowptr + (N_NODES + 1);
    int* bsum    = csr_src + N_EDGES;                          // 64

    hipMemsetAsync(deg, 0, N_NODES * sizeof(int), stream);

    const int eblk = (N_EDGES + 255) / 256;                    // 3125
    prep<<<32 + eblk, 256, 0, stream>>>(Wq, Wk, Wv, Ws, wtbf, ei, deg);

    const int nb = (N_NODES + 2047) / 2048;                    // 49
    scan_local<<<nb, 256, 0, stream>>>(deg, rowptr, bsum);
    add_off<<<(N_NODES + 255) / 256, 256, 0, stream>>>(rowptr, bsum);
    csr_fill<<<eblk, 256, 0, stream>>>(ei, rowptr, deg, csr_src);

    const int row_tiles = (N_NODES + 127) / 128;               // 782
    proj_mfma<<<row_tiles, 512, 0, stream>>>(x, wtbf, bq, bk, bv, bs,
                                             Qb, KVb, Sb);

    node_attn<<<(N_NODES + 3) / 4, 256, 0, stream>>>(rowptr, csr_src, Qb, KVb, Sb,
                                                     gamma, beta, out);
}

// Round 10
// 219.815 us; speedup vs baseline: 14.9494x; 1.0252x over previous
//
#include <hip/hip_runtime.h>
#include <math.h>

#define N_NODES 100000
#define N_EDGES 800000
#define HID 128
#define HEADS 4
#define HD 32

// 1/sqrt(32) * log2(e), folded into K projection; logits feed exp2f directly
#define KSCALE_L2E 0.2550348554422384f

typedef __attribute__((ext_vector_type(8))) short short8;
typedef __attribute__((ext_vector_type(4))) float f32x4;

__device__ __forceinline__ unsigned int f2bf(float f) {
    unsigned int u = __float_as_uint(f);
    u += 0x7FFFu + ((u >> 16) & 1u);
    return (u >> 16) & 0xFFFFu;   // RNE round to bf16
}
__device__ __forceinline__ float bf_lo(unsigned int u) { return __uint_as_float(u << 16); }
__device__ __forceinline__ float bf_hi(unsigned int u) { return __uint_as_float(u & 0xFFFF0000u); }

// ---------------------------------------------------------------------------
// prep: blocks 0..31 convert W fp32 -> bf16 transposed chunks; remaining
// blocks histogram edge destinations.
// ---------------------------------------------------------------------------
__global__ __launch_bounds__(256) void prep(
    const float* __restrict__ Wq, const float* __restrict__ Wk,
    const float* __restrict__ Wv, const float* __restrict__ Ws,
    uint4* __restrict__ wtbf, const int* __restrict__ ei,
    int* __restrict__ deg)
{
    const int b = blockIdx.x;
    if (b < 32) {
        int idx = b * 256 + threadIdx.x;        // [4][128][16]
        int m = idx >> 11, n = (idx >> 4) & 127, kc = idx & 15;
        const float* W = (m == 0) ? Wq : (m == 1) ? Wk : (m == 2) ? Wv : Ws;
        unsigned int h[8];
        #pragma unroll
        for (int j = 0; j < 8; ++j) h[j] = f2bf(W[(kc * 8 + j) * HID + n]);
        uint4 o;
        o.x = h[0] | (h[1] << 16);
        o.y = h[2] | (h[3] << 16);
        o.z = h[4] | (h[5] << 16);
        o.w = h[6] | (h[7] << 16);
        wtbf[idx] = o;
    } else {
        int e = (b - 32) * 256 + threadIdx.x;
        if (e < N_EDGES) atomicAdd(&deg[ei[N_EDGES + e]], 1);
    }
}

// ---------------------------------------------------------------------------
// MFMA projections, operand-swapped; 256 rows/block, each wave owns TWO
// 16-row groups so every W fragment feeds 2 MFMAs. W staged in two pairs
// (exactly 64 KB each). Outputs all bf16: Qb[128], KVb[256] (K*scale | V),
// Sb[128].
// ---------------------------------------------------------------------------
__global__ __launch_bounds__(512) void proj_mfma(
    const float* __restrict__ x, const uint4* __restrict__ wtbf,
    const float* __restrict__ bq, const float* __restrict__ bk,
    const float* __restrict__ bv, const float* __restrict__ bs,
    unsigned short* __restrict__ Qb, unsigned short* __restrict__ KVb,
    unsigned short* __restrict__ Sb)
{
    __shared__ uint4 wt[4096];          // 64 KB: TWO W matrices at a time

    const int rb   = blockIdx.x * 256;
    const int tid  = threadIdx.x;
    const int lane = tid & 63;
    const int w    = tid >> 6;          // 0..7
    const int r    = lane & 15;
    const int kg   = lane >> 4;

    // this wave's 32 x-rows (two 16-row groups) into bf16 fragments
    const int grow0 = rb + w * 32 + r;
    const int grow1 = grow0 + 16;
    short8 afr[2][4];
    #pragma unroll
    for (int rg = 0; rg < 2; ++rg) {
        const int grow = rg ? grow1 : grow0;
        #pragma unroll
        for (int s = 0; s < 4; ++s) {
            float4 a = make_float4(0.f, 0.f, 0.f, 0.f);
            float4 b = make_float4(0.f, 0.f, 0.f, 0.f);
            if (grow < N_NODES) {
                const float4* p = (const float4*)(x + (size_t)grow * HID + (s * 4 + kg) * 8);
                a = p[0]; b = p[1];
            }
            uint4 o;
            o.x = f2bf(a.x) | (f2bf(a.y) << 16);
            o.y = f2bf(a.z) | (f2bf(a.w) << 16);
            o.z = f2bf(b.x) | (f2bf(b.y) << 16);
            o.w = f2bf(b.z) | (f2bf(b.w) << 16);
            afr[rg][s] = *(short8*)&o;
        }
    }

    #pragma unroll
    for (int pair = 0; pair < 2; ++pair) {
        if (pair == 1) __syncthreads();          // prior pair's reads done
        // stage this pair's two W matrices: exactly 4096 uint4 (64 KB)
        #pragma unroll
        for (int it = 0; it < 8; ++it) {
            int cid = it * 512 + tid;            // [mh][n][kc] within pair
            int kc = cid & 15, n = (cid >> 4) & 127;
            wt[(cid & ~15) | (kc ^ (n & 7))] = wtbf[pair * 4096 + cid];
        }
        __syncthreads();

        #pragma unroll
        for (int mh = 0; mh < 2; ++mh) {
            const int m = pair * 2 + mh;
            const float* bias = (m == 0) ? bq : (m == 1) ? bk : (m == 2) ? bv : bs;
            const uint4* wtm = wt + mh * 2048;
            #pragma unroll
            for (int nt = 0; nt < 8; ++nt) {
                const int nrow = nt * 16 + r;
                const uint4* wrow = wtm + nrow * 16;
                f32x4 acc0, acc1;
                acc0[0]=0.f; acc0[1]=0.f; acc0[2]=0.f; acc0[3]=0.f;
                acc1[0]=0.f; acc1[1]=0.f; acc1[2]=0.f; acc1[3]=0.f;
                #pragma unroll
                for (int s = 0; s < 4; ++s) {
                    short8 bfr = *(const short8*)&wrow[(s * 4 + kg) ^ (nrow & 7)];
                    acc0 = __builtin_amdgcn_mfma_f32_16x16x32_bf16(bfr, afr[0][s], acc0, 0, 0, 0);
                    acc1 = __builtin_amdgcn_mfma_f32_16x16x32_bf16(bfr, afr[1][s], acc1, 0, 0, 0);
                }
                const int col = nt * 16 + kg * 4;
                float4 bi = *(const float4*)(bias + col);
                #pragma unroll
                for (int rg = 0; rg < 2; ++rg) {
                    const int grow = rg ? grow1 : grow0;
                    if (grow < N_NODES) {
                        f32x4 acc = rg ? acc1 : acc0;
                        float vx = acc[0] + bi.x, vy = acc[1] + bi.y;
                        float vz = acc[2] + bi.z, vw = acc[3] + bi.w;
                        if (m == 1) { vx *= KSCALE_L2E; vy *= KSCALE_L2E;
                                      vz *= KSCALE_L2E; vw *= KSCALE_L2E; }
                        uint2 pk;
                        pk.x = f2bf(vx) | (f2bf(vy) << 16);
                        pk.y = f2bf(vz) | (f2bf(vw) << 16);
                        unsigned short* dst =
                            (m == 0) ? (Qb + (size_t)grow * HID + col) :
                            (m == 1) ? (KVb + (size_t)grow * 256 + col) :
                            (m == 2) ? (KVb + (size_t)grow * 256 + 128 + col) :
                                       (Sb + (size_t)grow * HID + col);
                        *(uint2*)dst = pk;
                    }
                }
            }
        }
    }
}

// ---------------------------------------------------------------------------
// CSR build: hierarchical scan (49 blk local -> fused offset add), fill.
// ---------------------------------------------------------------------------
__global__ __launch_bounds__(256) void scan_local(const int* __restrict__ deg,
                                                  int* __restrict__ rowptr,
                                                  int* __restrict__ bsum)
{
    __shared__ int wsums[4];
    const int b = blockIdx.x, t = threadIdx.x, lane = t & 63, wid = t >> 6;
    const int base = b * 2048 + t * 8;
    int v[8], s = 0;
    #pragma unroll
    for (int j = 0; j < 8; ++j) {
        int i = base + j;
        v[j] = (i < N_NODES) ? deg[i] : 0;
        s += v[j];
    }
    const int tsum = s;
    int x = tsum;
    #pragma unroll
    for (int off = 1; off < 64; off <<= 1) {
        int t2 = __shfl_up(x, off);
        if (lane >= off) x += t2;
    }
    if (lane == 63) wsums[wid] = x;
    __syncthreads();
    int wpre = 0;
    #pragma unroll
    for (int ww = 0; ww < 4; ++ww) { if (ww < wid) wpre += wsums[ww]; }
    int run = wpre + x - tsum;
    #pragma unroll
    for (int j = 0; j < 8; ++j) {
        int i = base + j;
        if (i < N_NODES) rowptr[i] = run;
        run += v[j];
    }
    if (t == 0) bsum[b] = wsums[0] + wsums[1] + wsums[2] + wsums[3];
}

__global__ __launch_bounds__(256) void add_off(int* __restrict__ rowptr,
                                               const int* __restrict__ bsum)
{
    __shared__ int offs;
    const int t = threadIdx.x;
    const int tgt = blockIdx.x >> 3;       // 2048-node groups / 256-node blocks
    if (t < 64) {
        int v = (t < tgt) ? bsum[t] : 0;
        #pragma unroll
        for (int off = 1; off < 64; off <<= 1) v += __shfl_xor(v, off);
        if (t == 0) offs = v;
    }
    __syncthreads();
    int i = blockIdx.x * 256 + t;
    if (i < N_NODES) rowptr[i] += offs;
    if (blockIdx.x == 0 && t == 0) rowptr[N_NODES] = N_EDGES;
}

// fill: reuse deg (still intact) as countdown -> no fillctr array/memset
__global__ __launch_bounds__(256) void csr_fill(const int* __restrict__ ei,
                                                const int* __restrict__ rowptr,
                                                int* __restrict__ deg,
                                                int* __restrict__ csr_src)
{
    int e = blockIdx.x * 256 + threadIdx.x;
    if (e >= N_EDGES) return;
    int src = ei[e], dst = ei[N_EDGES + e];
    int old = atomicSub(&deg[dst], 1);
    csr_src[rowptr[dst] + old - 1] = src;
}

// ---------------------------------------------------------------------------
// Fused per-node attention: one wave per node; FOUR 16-lane edge slots
// (8 dims/lane, uint4 loads, 2 shfl levels per dot, shared exp2). Direct-exp
// softmax (logits bounded; K pre-scaled by 1/sqrt(32)*log2e). KV interleaved;
// slot merge at end; skip + LayerNorm fused. All inputs bf16.
// ---------------------------------------------------------------------------
__global__ __launch_bounds__(256) void node_attn(
    const int* __restrict__ rowptr, const int* __restrict__ csr_src,
    const unsigned short* __restrict__ Qb, const unsigned short* __restrict__ KVb,
    const unsigned short* __restrict__ Sb,
    const float* __restrict__ gamma, const float* __restrict__ beta,
    float* __restrict__ out)
{
    const int tid  = threadIdx.x;
    const int lane = tid & 63;
    const int node = blockIdx.x * 4 + (tid >> 6);
    if (node >= N_NODES) return;

    const int l16 = lane & 15;
    const int es  = lane >> 4;            // edge slot 0..3
    const int j8  = l16 * 8;              // dims j8..j8+7; head = l16>>2

    const int r0 = rowptr[node], r1 = rowptr[node + 1];

    uint4 qp = *(const uint4*)(Qb + (size_t)node * HID + j8);
    const float q0 = bf_lo(qp.x), q1 = bf_hi(qp.x);
    const float q2 = bf_lo(qp.y), q3 = bf_hi(qp.y);
    const float q4 = bf_lo(qp.z), q5 = bf_hi(qp.z);
    const float q6 = bf_lo(qp.w), q7 = bf_hi(qp.w);

    float den = 0.f;
    float a0 = 0.f, a1 = 0.f, a2 = 0.f, a3 = 0.f;
    float a4 = 0.f, a5 = 0.f, a6 = 0.f, a7 = 0.f;

    int p = r0 + es;
    uint4 kc = {0,0,0,0}, vc = {0,0,0,0};
    if (p < r1) {
        const unsigned short* base = KVb + (size_t)csr_src[p] * 256;
        kc = *(const uint4*)(base + j8);
        vc = *(const uint4*)(base + 128 + j8);
    }

    for (int it = r0; it < r1; it += 4) {
        uint4 kn = {0,0,0,0}, vn = {0,0,0,0};
        const int pn = p + 4;
        if (pn < r1) {
            const unsigned short* base = KVb + (size_t)csr_src[pn] * 256;
            kn = *(const uint4*)(base + j8);
            vn = *(const uint4*)(base + 128 + j8);
        }

        float t = q0 * bf_lo(kc.x) + q1 * bf_hi(kc.x)
                + q2 * bf_lo(kc.y) + q3 * bf_hi(kc.y)
                + q4 * bf_lo(kc.z) + q5 * bf_hi(kc.z)
                + q6 * bf_lo(kc.w) + q7 * bf_hi(kc.w);
        t += __shfl_xor(t, 1);
        t += __shfl_xor(t, 2);              // 4-lane head group complete

        float e = (p < r1) ? exp2f(t) : 0.f;
        den += e;
        a0 += e * bf_lo(vc.x); a1 += e * bf_hi(vc.x);
        a2 += e * bf_lo(vc.y); a3 += e * bf_hi(vc.y);
        a4 += e * bf_lo(vc.z); a5 += e * bf_hi(vc.z);
        a6 += e * bf_lo(vc.w); a7 += e * bf_hi(vc.w);

        p = pn; kc = kn; vc = vn;
    }

    // merge the 4 edge slots (lanes ^16, ^32)
    #pragma unroll
    for (int msk = 16; msk <= 32; msk <<= 1) {
        den += __shfl_xor(den, msk);
        a0 += __shfl_xor(a0, msk); a1 += __shfl_xor(a1, msk);
        a2 += __shfl_xor(a2, msk); a3 += __shfl_xor(a3, msk);
        a4 += __shfl_xor(a4, msk); a5 += __shfl_xor(a5, msk);
        a6 += __shfl_xor(a6, msk); a7 += __shfl_xor(a7, msk);
    }

    float inv = 1.0f / (den + 1e-16f);
    uint4 sp = *(const uint4*)(Sb + (size_t)node * HID + j8);
    float o0 = a0 * inv + bf_lo(sp.x), o1 = a1 * inv + bf_hi(sp.x);
    float o2 = a2 * inv + bf_lo(sp.y), o3 = a3 * inv + bf_hi(sp.y);
    float o4 = a4 * inv + bf_lo(sp.z), o5 = a5 * inv + bf_hi(sp.z);
    float o6 = a6 * inv + bf_lo(sp.w), o7 = a7 * inv + bf_hi(sp.w);

    // LayerNorm reduce over 16 lanes (all slots hold identical data now)
    float sum = (o0 + o1) + (o2 + o3) + (o4 + o5) + (o6 + o7);
    float sq  = o0*o0 + o1*o1 + o2*o2 + o3*o3 + o4*o4 + o5*o5 + o6*o6 + o7*o7;
    #pragma unroll
    for (int off = 1; off < 16; off <<= 1) {
        sum += __shfl_xor(sum, off);
        sq  += __shfl_xor(sq, off);
    }
    float mean = sum * (1.0f / 128.0f);
    float var  = sq * (1.0f / 128.0f) - mean * mean;
    float rstd = rsqrtf(var + 1e-5f);

    if (es == 0) {
        float4 g0 = *(const float4*)(gamma + j8);
        float4 g1 = *(const float4*)(gamma + j8 + 4);
        float4 b0 = *(const float4*)(beta + j8);
        float4 b1 = *(const float4*)(beta + j8 + 4);
        float4 w0, w1;
        w0.x = (o0 - mean) * rstd * g0.x + b0.x;
        w0.y = (o1 - mean) * rstd * g0.y + b0.y;
        w0.z = (o2 - mean) * rstd * g0.z + b0.z;
        w0.w = (o3 - mean) * rstd * g0.w + b0.w;
        w1.x = (o4 - mean) * rstd * g1.x + b1.x;
        w1.y = (o5 - mean) * rstd * g1.y + b1.y;
        w1.z = (o6 - mean) * rstd * g1.z + b1.z;
        w1.w = (o7 - mean) * rstd * g1.w + b1.w;
        float* op = out + (size_t)node * HID + j8;
        *(float4*)op = w0;
        *(float4*)(op + 4) = w1;
    }
}

// ---------------------------------------------------------------------------
extern "C" void kernel_launch(void* const* d_in, const int* in_sizes, int n_in,
                              void* d_out, int out_size, void* d_ws, size_t ws_size,
                              hipStream_t stream) {
    const float* x  = (const float*)d_in[0];
    const int*   ei = (const int*)d_in[1];
    const float* Wq = (const float*)d_in[2];
    const float* bq = (const float*)d_in[3];
    const float* Wk = (const float*)d_in[4];
    const float* bk = (const float*)d_in[5];
    const float* Wv = (const float*)d_in[6];
    const float* bv = (const float*)d_in[7];
    const float* Ws = (const float*)d_in[8];
    const float* bs = (const float*)d_in[9];
    const float* gamma = (const float*)d_in[10];
    const float* beta  = (const float*)d_in[11];
    float* out = (float*)d_out;

    // workspace layout (all bf16 feature buffers)
    unsigned short* Qb  = (unsigned short*)d_ws;               // [N,128]
    unsigned short* KVb = Qb + (size_t)N_NODES * HID;          // [N,256]
    unsigned short* Sb  = KVb + (size_t)N_NODES * 256;         // [N,128]
    uint4* wtbf  = (uint4*)(Sb + (size_t)N_NODES * HID);       // [4*128*16]
    int* deg     = (int*)(wtbf + 4 * 128 * 16);
    int* rowptr  = deg + N_NODES;                              // N+1
    int* csr_src = rowptr + (N_NODES + 1);
    int* bsum    = csr_src + N_EDGES;                          // 64

    hipMemsetAsync(deg, 0, N_NODES * sizeof(int), stream);

    const int eblk = (N_EDGES + 255) / 256;                    // 3125
    prep<<<32 + eblk, 256, 0, stream>>>(Wq, Wk, Wv, Ws, wtbf, ei, deg);

    const int nb = (N_NODES + 2047) / 2048;                    // 49
    scan_local<<<nb, 256, 0, stream>>>(deg, rowptr, bsum);
    add_off<<<(N_NODES + 255) / 256, 256, 0, stream>>>(rowptr, bsum);
    csr_fill<<<eblk, 256, 0, stream>>>(ei, rowptr, deg, csr_src);

    const int row_tiles = (N_NODES + 255) / 256;               // 391
    proj_mfma<<<row_tiles, 512, 0, stream>>>(x, wtbf, bq, bk, bv, bs,
                                             Qb, KVb, Sb);

    node_attn<<<(N_NODES + 3) / 4, 256, 0, stream>>>(rowptr, csr_src, Qb, KVb, Sb,
                                                     gamma, beta, out);
}